// Round 1
// baseline (1007.005 us; speedup 1.0000x reference)
//
#include <hip/hip_runtime.h>
#include <math.h>

#define BN_EPS 1e-5f

__device__ __forceinline__ float4 fma4(float s, float4 a, float4 b) {
    return make_float4(fmaf(s, a.x, b.x), fmaf(s, a.y, b.y),
                       fmaf(s, a.z, b.z), fmaf(s, a.w, b.w));
}

// ---------------- degree / norm preprocessing ----------------

// wdeg[c] += ew[e]; cnt[c] += 1  over edges (col = ei[E+e])
__global__ void count_k(const int* __restrict__ ei, const float* __restrict__ ew,
                        float* __restrict__ wdeg, int* __restrict__ cnt, int E) {
    int e = blockIdx.x * blockDim.x + threadIdx.x;
    if (e >= E) return;
    int c = ei[E + e];
    atomicAdd(&wdeg[c], ew[e]);
    atomicAdd(&cnt[c], 1);
}

// in-place: wdeg -> dinv = 1/sqrt(wdeg + 1)   (deg always > 0 due to self-loop)
__global__ void dinv_k(float* __restrict__ wdeg, int n) {
    int i = blockIdx.x * blockDim.x + threadIdx.x;
    if (i >= n) return;
    wdeg[i] = 1.0f / sqrtf(wdeg[i] + 1.0f);
}

// two-level exclusive scan of cnt[n] -> rptr[0..n], cursor copy
__global__ void scanA(const int* __restrict__ cnt, int* __restrict__ bsums, int n) {
    __shared__ int s[256];
    int b = blockIdx.x, t = threadIdx.x;
    int base = b * 1024 + t * 4;
    int sum = 0;
#pragma unroll
    for (int j = 0; j < 4; ++j) { int idx = base + j; if (idx < n) sum += cnt[idx]; }
    s[t] = sum;
    __syncthreads();
    for (int off = 128; off > 0; off >>= 1) {
        if (t < off) s[t] += s[t + off];
        __syncthreads();
    }
    if (t == 0) bsums[b] = s[0];
}

__global__ void scanB(const int* __restrict__ bsums, int* __restrict__ boffs,
                      int nb, int* __restrict__ rptr_last) {
    if (threadIdx.x == 0 && blockIdx.x == 0) {
        int run = 0;
        for (int i = 0; i < nb; ++i) { boffs[i] = run; run += bsums[i]; }
        rptr_last[0] = run;
    }
}

__global__ void scanC(const int* __restrict__ cnt, const int* __restrict__ boffs,
                      int* __restrict__ rptr, int* __restrict__ cursor, int n) {
    __shared__ int s[256];
    int b = blockIdx.x, t = threadIdx.x;
    int base = b * 1024 + t * 4;
    int v[4], loc[4];
    int sum = 0;
#pragma unroll
    for (int j = 0; j < 4; ++j) {
        int idx = base + j;
        v[j] = (idx < n) ? cnt[idx] : 0;
        loc[j] = sum;
        sum += v[j];
    }
    s[t] = sum;
    __syncthreads();
    for (int off = 1; off < 256; off <<= 1) {
        int x = (t >= off) ? s[t - off] : 0;
        __syncthreads();
        s[t] += x;
        __syncthreads();
    }
    int excl = s[t] - sum;
    int off0 = boffs[b] + excl;
#pragma unroll
    for (int j = 0; j < 4; ++j) {
        int idx = base + j;
        if (idx < n) { int p = off0 + loc[j]; rptr[idx] = p; cursor[idx] = p; }
    }
}

// append edges into CSR buckets; store row index and final norm
__global__ void scatter_k(const int* __restrict__ ei, const float* __restrict__ ew,
                          const float* __restrict__ dinv, int* __restrict__ cursor,
                          int* __restrict__ srow, float* __restrict__ snorm, int E) {
    int e = blockIdx.x * blockDim.x + threadIdx.x;
    if (e >= E) return;
    int r = ei[e], c = ei[E + e];
    int p = atomicAdd(&cursor[c], 1);
    srow[p] = r;
    snorm[p] = dinv[r] * ew[e] * dinv[c];
}

// ---------------- dense matmul h = x @ w ----------------
// 64 rows/block, w staged in LDS as float4, x rows staged padded.
template <int DIN, int DOUT>
__global__ __launch_bounds__(256) void matmul_k(const float* __restrict__ x,
                                                const float* __restrict__ w,
                                                float* __restrict__ h, int n) {
    constexpr int RPB = 64;
    constexpr int XS = DIN + 4;      // pad keeps scalar reads ~conflict-free, float4-aligned
    constexpr int J = DOUT / 16;     // float4 outputs per thread
    __shared__ float xs[RPB * XS];
    __shared__ float4 ws4[DIN * (DOUT / 4)];
    int t = threadIdx.x;
    int row0 = blockIdx.x * RPB;

    for (int i = t; i < DIN * DOUT / 4; i += 256) ws4[i] = ((const float4*)w)[i];
    for (int i = t; i < RPB * DIN / 4; i += 256) {
        int r = i / (DIN / 4), kq = i % (DIN / 4);
        int gr = row0 + r;
        float4 xv = (gr < n) ? ((const float4*)x)[(size_t)gr * (DIN / 4) + kq]
                             : make_float4(0.f, 0.f, 0.f, 0.f);
        *(float4*)&xs[r * XS + kq * 4] = xv;
    }
    __syncthreads();

    int r = t >> 2, cg = t & 3;
    float4 acc[J];
#pragma unroll
    for (int j = 0; j < J; ++j) acc[j] = make_float4(0.f, 0.f, 0.f, 0.f);

    for (int k = 0; k < DIN; ++k) {
        float xv = xs[r * XS + k];
#pragma unroll
        for (int j = 0; j < J; ++j) {
            float4 wv = ws4[k * (DOUT / 4) + cg + 4 * j];
            acc[j] = fma4(xv, wv, acc[j]);
        }
    }
    int gr = row0 + r;
    if (gr < n) {
#pragma unroll
        for (int j = 0; j < J; ++j)
            ((float4*)h)[(size_t)gr * (DOUT / 4) + cg + 4 * j] = acc[j];
    }
}

// ---------------- fused aggregate + self-loop + bias + BN + ReLU ----------------
template <int D>
__global__ __launch_bounds__(256) void agg_k(const float* __restrict__ h,
                                             const int* __restrict__ rptr,
                                             const int* __restrict__ srow,
                                             const float* __restrict__ snorm,
                                             const float* __restrict__ dinv,
                                             const float* __restrict__ bias,
                                             const float* __restrict__ g,
                                             const float* __restrict__ be,
                                             const float* __restrict__ m,
                                             const float* __restrict__ v,
                                             float* __restrict__ y, int n) {
    constexpr int TPN = D / 4;  // threads per node
    int npb = 256 / TPN;
    int node = blockIdx.x * npb + (int)(threadIdx.x / TPN);
    int lc = (int)(threadIdx.x % TPN);  // float4 column
    if (node >= n) return;

    int s = rptr[node], e = rptr[node + 1];
    float4 acc = make_float4(0.f, 0.f, 0.f, 0.f);
    for (int i = s; i < e; ++i) {
        int r = srow[i];
        float wv = snorm[i];
        float4 hv = ((const float4*)h)[(size_t)r * TPN + lc];
        acc = fma4(wv, hv, acc);
    }
    float dv = dinv[node];
    float sn = dv * dv;
    float4 hs = ((const float4*)h)[(size_t)node * TPN + lc];
    float4 bb = ((const float4*)bias)[lc];
    float4 gg = ((const float4*)g)[lc];
    float4 ee = ((const float4*)be)[lc];
    float4 mm = ((const float4*)m)[lc];
    float4 vv = ((const float4*)v)[lc];

    float4 o;
    o.x = acc.x + sn * hs.x + bb.x;
    o.y = acc.y + sn * hs.y + bb.y;
    o.z = acc.z + sn * hs.z + bb.z;
    o.w = acc.w + sn * hs.w + bb.w;

    float4 res;
    res.x = fmaxf((o.x - mm.x) * (gg.x / sqrtf(vv.x + BN_EPS)) + ee.x, 0.f);
    res.y = fmaxf((o.y - mm.y) * (gg.y / sqrtf(vv.y + BN_EPS)) + ee.y, 0.f);
    res.z = fmaxf((o.z - mm.z) * (gg.z / sqrtf(vv.z + BN_EPS)) + ee.z, 0.f);
    res.w = fmaxf((o.w - mm.w) * (gg.w / sqrtf(vv.w + BN_EPS)) + ee.w, 0.f);

    ((float4*)y)[(size_t)node * TPN + lc] = res;
}

// ---------------- global mean pool (batch is sorted) ----------------
__global__ void pool_k(const float* __restrict__ y, const int* __restrict__ batch,
                       float* __restrict__ pooled, int n) {
    int gph = blockIdx.x;  // 0..63
    int lo = 0, hi = n;
    while (lo < hi) { int mid = (lo + hi) >> 1; if (batch[mid] < gph) lo = mid + 1; else hi = mid; }
    int s = lo;
    lo = 0; hi = n;
    while (lo < hi) { int mid = (lo + hi) >> 1; if (batch[mid] < gph + 1) lo = mid + 1; else hi = mid; }
    int e = lo;
    int t = threadIdx.x;  // 128 threads, one feature each
    float acc = 0.f;
    for (int i = s; i < e; ++i) acc += y[(size_t)i * 128 + t];
    float c = (e - s) > 0 ? (float)(e - s) : 1.0f;
    pooled[gph * 128 + t] = acc / c;
}

// ---------------- final FCs (tiny) ----------------
__global__ __launch_bounds__(256) void fc_k(const float* __restrict__ pooled,
                                            const float* __restrict__ fcw,
                                            const float* __restrict__ fcb,
                                            const float* __restrict__ ow,
                                            const float* __restrict__ ob,
                                            float* __restrict__ out) {
    __shared__ float ps[64 * 128];
    __shared__ float hs[64 * 64];
    int t = threadIdx.x;
    for (int i = t; i < 64 * 128; i += 256) ps[i] = pooled[i];
    __syncthreads();
    for (int idx = t; idx < 64 * 64; idx += 256) {
        int gph = idx >> 6, j = idx & 63;
        float a = fcb[j];
        for (int k = 0; k < 128; ++k) a = fmaf(ps[gph * 128 + k], fcw[k * 64 + j], a);
        hs[idx] = fmaxf(a, 0.f);
    }
    __syncthreads();
    if (t < 64) {
        float a = ob[0];
        for (int j = 0; j < 64; ++j) a = fmaf(hs[t * 64 + j], ow[j], a);
        out[t] = a;
    }
}

extern "C" void kernel_launch(void* const* d_in, const int* in_sizes, int n_in,
                              void* d_out, int out_size, void* d_ws, size_t ws_size,
                              hipStream_t stream) {
    const float* x     = (const float*)d_in[0];
    const int*   ei    = (const int*)d_in[1];
    const float* ew    = (const float*)d_in[2];
    const int*   batch = (const int*)d_in[3];
    const float* w1 = (const float*)d_in[4],  *b1 = (const float*)d_in[5];
    const float* g1 = (const float*)d_in[6],  *be1 = (const float*)d_in[7];
    const float* m1 = (const float*)d_in[8],  *v1 = (const float*)d_in[9];
    const float* w2 = (const float*)d_in[10], *b2 = (const float*)d_in[11];
    const float* g2 = (const float*)d_in[12], *be2 = (const float*)d_in[13];
    const float* m2 = (const float*)d_in[14], *v2 = (const float*)d_in[15];
    const float* w3 = (const float*)d_in[16], *b3 = (const float*)d_in[17];
    const float* g3 = (const float*)d_in[18], *be3 = (const float*)d_in[19];
    const float* m3 = (const float*)d_in[20], *v3 = (const float*)d_in[21];
    const float* fcw = (const float*)d_in[22], *fcb = (const float*)d_in[23];
    const float* ow  = (const float*)d_in[24], *ob  = (const float*)d_in[25];
    float* out = (float*)d_out;

    const int N = in_sizes[3];
    const int E = in_sizes[2];

    // workspace layout (floats/ints), ~117 MB total
    float* A    = (float*)d_ws;            // N x 128 (h buffer)
    float* Bf   = A + (size_t)N * 128;     // N x 128 (y buffer)
    float* dinv = Bf + (size_t)N * 128;    // N   (wdeg -> dinv in place)
    int*   cnt    = (int*)(dinv + N);      // N
    int*   rptr   = cnt + N;               // N+1
    int*   cursor = rptr + (N + 1);        // N
    int*   bsums  = cursor + N;            // 1024
    int*   boffs  = bsums + 1024;          // 1024
    int*   srow   = boffs + 1024;          // E
    float* snorm  = (float*)(srow + E);    // E
    float* pooled = snorm + E;             // 64*128

    hipMemsetAsync(dinv, 0, (size_t)N * sizeof(float), stream);
    hipMemsetAsync(cnt, 0, (size_t)N * sizeof(int), stream);

    int eb = (E + 255) / 256;
    int nb = (N + 255) / 256;
    int nsb = (N + 1023) / 1024;

    count_k<<<eb, 256, 0, stream>>>(ei, ew, dinv, cnt, E);
    dinv_k<<<nb, 256, 0, stream>>>(dinv, N);
    scanA<<<nsb, 256, 0, stream>>>(cnt, bsums, N);
    scanB<<<1, 64, 0, stream>>>(bsums, boffs, nsb, rptr + N);
    scanC<<<nsb, 256, 0, stream>>>(cnt, boffs, rptr, cursor, N);
    scatter_k<<<eb, 256, 0, stream>>>(ei, ew, dinv, cursor, srow, snorm, E);

    // layer 1: 64 -> 32
    matmul_k<64, 32><<<(N + 63) / 64, 256, 0, stream>>>(x, w1, A, N);
    agg_k<32><<<(N + 31) / 32, 256, 0, stream>>>(A, rptr, srow, snorm, dinv,
                                                 b1, g1, be1, m1, v1, Bf, N);
    // layer 2: 32 -> 64
    matmul_k<32, 64><<<(N + 63) / 64, 256, 0, stream>>>(Bf, w2, A, N);
    agg_k<64><<<(N + 15) / 16, 256, 0, stream>>>(A, rptr, srow, snorm, dinv,
                                                 b2, g2, be2, m2, v2, Bf, N);
    // layer 3: 64 -> 128
    matmul_k<64, 128><<<(N + 63) / 64, 256, 0, stream>>>(Bf, w3, A, N);
    agg_k<128><<<(N + 7) / 8, 256, 0, stream>>>(A, rptr, srow, snorm, dinv,
                                                b3, g3, be3, m3, v3, Bf, N);

    pool_k<<<64, 128, 0, stream>>>(Bf, batch, pooled, N);
    fc_k<<<1, 256, 0, stream>>>(pooled, fcw, fcb, ow, ob, out);
}

// Round 2
// 667.206 us; speedup vs baseline: 1.5093x; 1.5093x over previous
//
#include <hip/hip_runtime.h>
#include <math.h>

#define BN_EPS 1e-5f

__device__ __forceinline__ float4 fma4(float s, float4 a, float4 b) {
    return make_float4(fmaf(s, a.x, b.x), fmaf(s, a.y, b.y),
                       fmaf(s, a.z, b.z), fmaf(s, a.w, b.w));
}

// ---------------- degree / norm preprocessing ----------------

__global__ void count_k(const int* __restrict__ ei, const float* __restrict__ ew,
                        float* __restrict__ wdeg, int* __restrict__ cnt, int E) {
    int e = blockIdx.x * blockDim.x + threadIdx.x;
    if (e >= E) return;
    int c = ei[E + e];
    atomicAdd(&wdeg[c], ew[e]);
    atomicAdd(&cnt[c], 1);
}

__global__ void dinv_k(float* __restrict__ wdeg, int n) {
    int i = blockIdx.x * blockDim.x + threadIdx.x;
    if (i >= n) return;
    wdeg[i] = 1.0f / sqrtf(wdeg[i] + 1.0f);
}

// two-level exclusive scan of cnt[n] -> rptr[0..n], cursor copy
__global__ void scanA(const int* __restrict__ cnt, int* __restrict__ bsums, int n) {
    __shared__ int s[256];
    int b = blockIdx.x, t = threadIdx.x;
    int base = b * 1024 + t * 4;
    int sum = 0;
#pragma unroll
    for (int j = 0; j < 4; ++j) { int idx = base + j; if (idx < n) sum += cnt[idx]; }
    s[t] = sum;
    __syncthreads();
    for (int off = 128; off > 0; off >>= 1) {
        if (t < off) s[t] += s[t + off];
        __syncthreads();
    }
    if (t == 0) bsums[b] = s[0];
}

__global__ void scanB(const int* __restrict__ bsums, int* __restrict__ boffs,
                      int nb, int* __restrict__ rptr_last) {
    if (threadIdx.x == 0 && blockIdx.x == 0) {
        int run = 0;
        for (int i = 0; i < nb; ++i) { boffs[i] = run; run += bsums[i]; }
        rptr_last[0] = run;
    }
}

__global__ void scanC(const int* __restrict__ cnt, const int* __restrict__ boffs,
                      int* __restrict__ rptr, int* __restrict__ cursor, int n) {
    __shared__ int s[256];
    int b = blockIdx.x, t = threadIdx.x;
    int base = b * 1024 + t * 4;
    int v[4], loc[4];
    int sum = 0;
#pragma unroll
    for (int j = 0; j < 4; ++j) {
        int idx = base + j;
        v[j] = (idx < n) ? cnt[idx] : 0;
        loc[j] = sum;
        sum += v[j];
    }
    s[t] = sum;
    __syncthreads();
    for (int off = 1; off < 256; off <<= 1) {
        int x = (t >= off) ? s[t - off] : 0;
        __syncthreads();
        s[t] += x;
        __syncthreads();
    }
    int excl = s[t] - sum;
    int off0 = boffs[b] + excl;
#pragma unroll
    for (int j = 0; j < 4; ++j) {
        int idx = base + j;
        if (idx < n) { int p = off0 + loc[j]; rptr[idx] = p; cursor[idx] = p; }
    }
}

__global__ void scatter_k(const int* __restrict__ ei, const float* __restrict__ ew,
                          const float* __restrict__ dinv, int* __restrict__ cursor,
                          int* __restrict__ srow, float* __restrict__ snorm, int E) {
    int e = blockIdx.x * blockDim.x + threadIdx.x;
    if (e >= E) return;
    int r = ei[e], c = ei[E + e];
    int p = atomicAdd(&cursor[c], 1);
    srow[p] = r;
    snorm[p] = dinv[r] * ew[e] * dinv[c];
}

// ---------------- dense matmul h = x @ w ----------------
template <int DIN, int DOUT>
__global__ __launch_bounds__(256) void matmul_k(const float* __restrict__ x,
                                                const float* __restrict__ w,
                                                float* __restrict__ h, int n) {
    constexpr int RPB = 64;
    constexpr int XS = DIN + 4;
    constexpr int J = DOUT / 16;
    __shared__ float xs[RPB * XS];
    __shared__ float4 ws4[DIN * (DOUT / 4)];
    int t = threadIdx.x;
    int row0 = blockIdx.x * RPB;

    for (int i = t; i < DIN * DOUT / 4; i += 256) ws4[i] = ((const float4*)w)[i];
    for (int i = t; i < RPB * DIN / 4; i += 256) {
        int r = i / (DIN / 4), kq = i % (DIN / 4);
        int gr = row0 + r;
        float4 xv = (gr < n) ? ((const float4*)x)[(size_t)gr * (DIN / 4) + kq]
                             : make_float4(0.f, 0.f, 0.f, 0.f);
        *(float4*)&xs[r * XS + kq * 4] = xv;
    }
    __syncthreads();

    int r = t >> 2, cg = t & 3;
    float4 acc[J];
#pragma unroll
    for (int j = 0; j < J; ++j) acc[j] = make_float4(0.f, 0.f, 0.f, 0.f);

    for (int k = 0; k < DIN; ++k) {
        float xv = xs[r * XS + k];
#pragma unroll
        for (int j = 0; j < J; ++j) {
            float4 wv = ws4[k * (DOUT / 4) + cg + 4 * j];
            acc[j] = fma4(xv, wv, acc[j]);
        }
    }
    int gr = row0 + r;
    if (gr < n) {
#pragma unroll
        for (int j = 0; j < J; ++j)
            ((float4*)h)[(size_t)gr * (DOUT / 4) + cg + 4 * j] = acc[j];
    }
}

// ---------------- fused aggregate + self-loop + bias + BN + ReLU ----------------
template <int D>
__global__ __launch_bounds__(256) void agg_k(const float* __restrict__ h,
                                             const int* __restrict__ rptr,
                                             const int* __restrict__ srow,
                                             const float* __restrict__ snorm,
                                             const float* __restrict__ dinv,
                                             const float* __restrict__ bias,
                                             const float* __restrict__ g,
                                             const float* __restrict__ be,
                                             const float* __restrict__ m,
                                             const float* __restrict__ v,
                                             float* __restrict__ y, int n) {
    constexpr int TPN = D / 4;
    int npb = 256 / TPN;
    int node = blockIdx.x * npb + (int)(threadIdx.x / TPN);
    int lc = (int)(threadIdx.x % TPN);
    if (node >= n) return;

    int s = rptr[node], e = rptr[node + 1];
    float4 acc = make_float4(0.f, 0.f, 0.f, 0.f);
    for (int i = s; i < e; ++i) {
        int r = srow[i];
        float wv = snorm[i];
        float4 hv = ((const float4*)h)[(size_t)r * TPN + lc];
        acc = fma4(wv, hv, acc);
    }
    float dv = dinv[node];
    float sn = dv * dv;
    float4 hs = ((const float4*)h)[(size_t)node * TPN + lc];
    float4 bb = ((const float4*)bias)[lc];
    float4 gg = ((const float4*)g)[lc];
    float4 ee = ((const float4*)be)[lc];
    float4 mm = ((const float4*)m)[lc];
    float4 vv = ((const float4*)v)[lc];

    float4 o;
    o.x = acc.x + sn * hs.x + bb.x;
    o.y = acc.y + sn * hs.y + bb.y;
    o.z = acc.z + sn * hs.z + bb.z;
    o.w = acc.w + sn * hs.w + bb.w;

    float4 res;
    res.x = fmaxf((o.x - mm.x) * (gg.x / sqrtf(vv.x + BN_EPS)) + ee.x, 0.f);
    res.y = fmaxf((o.y - mm.y) * (gg.y / sqrtf(vv.y + BN_EPS)) + ee.y, 0.f);
    res.z = fmaxf((o.z - mm.z) * (gg.z / sqrtf(vv.z + BN_EPS)) + ee.z, 0.f);
    res.w = fmaxf((o.w - mm.w) * (gg.w / sqrtf(vv.w + BN_EPS)) + ee.w, 0.f);

    ((float4*)y)[(size_t)node * TPN + lc] = res;
}

// ---------------- parallel global mean pool (batch sorted) ----------------
// stage 1: tiled accumulation with atomic flush at graph boundaries
__global__ __launch_bounds__(256) void pool2_k(const float* __restrict__ y,
                                               const int* __restrict__ batch,
                                               float* __restrict__ sums, int n) {
    const int NPB = 256;  // nodes per block
    int node0 = blockIdx.x * NPB;
    int lc = threadIdx.x & 31;   // float4 column (32 groups of 4 = 128 feats)
    int nr = threadIdx.x >> 5;   // node lane 0..7
    int end = node0 + NPB < n ? node0 + NPB : n;

    float4 acc = make_float4(0.f, 0.f, 0.f, 0.f);
    int curg = -1;
    for (int i = node0 + nr; i < end; i += 8) {
        int gph = batch[i];
        if (gph != curg) {
            if (curg >= 0) {
                float* dst = &sums[curg * 128 + lc * 4];
                atomicAdd(dst + 0, acc.x);
                atomicAdd(dst + 1, acc.y);
                atomicAdd(dst + 2, acc.z);
                atomicAdd(dst + 3, acc.w);
            }
            acc = make_float4(0.f, 0.f, 0.f, 0.f);
            curg = gph;
        }
        float4 hv = ((const float4*)y)[(size_t)i * 32 + lc];
        acc.x += hv.x; acc.y += hv.y; acc.z += hv.z; acc.w += hv.w;
    }
    if (curg >= 0) {
        float* dst = &sums[curg * 128 + lc * 4];
        atomicAdd(dst + 0, acc.x);
        atomicAdd(dst + 1, acc.y);
        atomicAdd(dst + 2, acc.z);
        atomicAdd(dst + 3, acc.w);
    }
}

// per-graph node counts via binary search on sorted batch
__global__ void gcnt_k(const int* __restrict__ batch, float* __restrict__ rcnt, int n) {
    int gph = threadIdx.x;  // 64 threads
    if (gph >= 64) return;
    int lo = 0, hi = n;
    while (lo < hi) { int mid = (lo + hi) >> 1; if (batch[mid] < gph) lo = mid + 1; else hi = mid; }
    int s = lo;
    lo = 0; hi = n;
    while (lo < hi) { int mid = (lo + hi) >> 1; if (batch[mid] < gph + 1) lo = mid + 1; else hi = mid; }
    int c = lo - s;
    rcnt[gph] = 1.0f / (c > 0 ? (float)c : 1.0f);
}

// ---------------- final FCs (tiny) ----------------
__global__ __launch_bounds__(256) void fc_k(const float* __restrict__ sums,
                                            const float* __restrict__ rcnt,
                                            const float* __restrict__ fcw,
                                            const float* __restrict__ fcb,
                                            const float* __restrict__ ow,
                                            const float* __restrict__ ob,
                                            float* __restrict__ out) {
    __shared__ float ps[64 * 128];
    __shared__ float hs[64 * 64];
    int t = threadIdx.x;
    for (int i = t; i < 64 * 128; i += 256) ps[i] = sums[i] * rcnt[i >> 7];
    __syncthreads();
    for (int idx = t; idx < 64 * 64; idx += 256) {
        int gph = idx >> 6, j = idx & 63;
        float a = fcb[j];
        for (int k = 0; k < 128; ++k) a = fmaf(ps[gph * 128 + k], fcw[k * 64 + j], a);
        hs[idx] = fmaxf(a, 0.f);
    }
    __syncthreads();
    if (t < 64) {
        float a = ob[0];
        for (int j = 0; j < 64; ++j) a = fmaf(hs[t * 64 + j], ow[j], a);
        out[t] = a;
    }
}

extern "C" void kernel_launch(void* const* d_in, const int* in_sizes, int n_in,
                              void* d_out, int out_size, void* d_ws, size_t ws_size,
                              hipStream_t stream) {
    const float* x     = (const float*)d_in[0];
    const int*   ei    = (const int*)d_in[1];
    const float* ew    = (const float*)d_in[2];
    const int*   batch = (const int*)d_in[3];
    const float* w1 = (const float*)d_in[4],  *b1 = (const float*)d_in[5];
    const float* g1 = (const float*)d_in[6],  *be1 = (const float*)d_in[7];
    const float* m1 = (const float*)d_in[8],  *v1 = (const float*)d_in[9];
    const float* w2 = (const float*)d_in[10], *b2 = (const float*)d_in[11];
    const float* g2 = (const float*)d_in[12], *be2 = (const float*)d_in[13];
    const float* m2 = (const float*)d_in[14], *v2 = (const float*)d_in[15];
    const float* w3 = (const float*)d_in[16], *b3 = (const float*)d_in[17];
    const float* g3 = (const float*)d_in[18], *be3 = (const float*)d_in[19];
    const float* m3 = (const float*)d_in[20], *v3 = (const float*)d_in[21];
    const float* fcw = (const float*)d_in[22], *fcb = (const float*)d_in[23];
    const float* ow  = (const float*)d_in[24], *ob  = (const float*)d_in[25];
    float* out = (float*)d_out;

    const int N = in_sizes[3];
    const int E = in_sizes[2];

    // workspace layout
    float* A    = (float*)d_ws;            // N x 128
    float* Bf   = A + (size_t)N * 128;     // N x 128
    float* dinv = Bf + (size_t)N * 128;    // N
    int*   cnt    = (int*)(dinv + N);      // N
    int*   rptr   = cnt + N;               // N+1
    int*   cursor = rptr + (N + 1);        // N
    int*   bsums  = cursor + N;            // 1024
    int*   boffs  = bsums + 1024;          // 1024
    int*   srow   = boffs + 1024;          // E
    float* snorm  = (float*)(srow + E);    // E
    float* sums   = snorm + E;             // 64*128
    float* rcnt   = sums + 64 * 128;       // 64

    hipMemsetAsync(dinv, 0, (size_t)N * sizeof(float), stream);
    hipMemsetAsync(cnt, 0, (size_t)N * sizeof(int), stream);
    hipMemsetAsync(sums, 0, 64 * 128 * sizeof(float), stream);

    int eb = (E + 255) / 256;
    int nb = (N + 255) / 256;
    int nsb = (N + 1023) / 1024;

    count_k<<<eb, 256, 0, stream>>>(ei, ew, dinv, cnt, E);
    dinv_k<<<nb, 256, 0, stream>>>(dinv, N);
    scanA<<<nsb, 256, 0, stream>>>(cnt, bsums, N);
    scanB<<<1, 64, 0, stream>>>(bsums, boffs, nsb, rptr + N);
    scanC<<<nsb, 256, 0, stream>>>(cnt, boffs, rptr, cursor, N);
    scatter_k<<<eb, 256, 0, stream>>>(ei, ew, dinv, cursor, srow, snorm, E);

    matmul_k<64, 32><<<(N + 63) / 64, 256, 0, stream>>>(x, w1, A, N);
    agg_k<32><<<(N + 31) / 32, 256, 0, stream>>>(A, rptr, srow, snorm, dinv,
                                                 b1, g1, be1, m1, v1, Bf, N);
    matmul_k<32, 64><<<(N + 63) / 64, 256, 0, stream>>>(Bf, w2, A, N);
    agg_k<64><<<(N + 15) / 16, 256, 0, stream>>>(A, rptr, srow, snorm, dinv,
                                                 b2, g2, be2, m2, v2, Bf, N);
    matmul_k<64, 128><<<(N + 63) / 64, 256, 0, stream>>>(Bf, w3, A, N);
    agg_k<128><<<(N + 7) / 8, 256, 0, stream>>>(A, rptr, srow, snorm, dinv,
                                                b3, g3, be3, m3, v3, Bf, N);

    pool2_k<<<(N + 255) / 256, 256, 0, stream>>>(Bf, batch, sums, N);
    gcnt_k<<<1, 64, 0, stream>>>(batch, rcnt, N);
    fc_k<<<1, 256, 0, stream>>>(sums, rcnt, fcw, fcb, ow, ob, out);
}

// Round 3
// 601.697 us; speedup vs baseline: 1.6736x; 1.1089x over previous
//
#include <hip/hip_runtime.h>
#include <math.h>

#define BN_EPS 1e-5f

__device__ __forceinline__ float4 fma4(float s, float4 a, float4 b) {
    return make_float4(fmaf(s, a.x, b.x), fmaf(s, a.y, b.y),
                       fmaf(s, a.z, b.z), fmaf(s, a.w, b.w));
}

// ---------------- degree / CSR preprocessing ----------------

// cnt[c] += 1 over edges (1 atomic per edge)
__global__ void hist_k(const int* __restrict__ ei, int* __restrict__ cnt, int E) {
    int e = blockIdx.x * blockDim.x + threadIdx.x;
    if (e >= E) return;
    atomicAdd(&cnt[ei[E + e]], 1);
}

// two-level exclusive scan of cnt[n] -> rptr[0..n], cursor copy
__global__ void scanA(const int* __restrict__ cnt, int* __restrict__ bsums, int n) {
    __shared__ int s[256];
    int b = blockIdx.x, t = threadIdx.x;
    int base = b * 1024 + t * 4;
    int sum = 0;
#pragma unroll
    for (int j = 0; j < 4; ++j) { int idx = base + j; if (idx < n) sum += cnt[idx]; }
    s[t] = sum;
    __syncthreads();
    for (int off = 128; off > 0; off >>= 1) {
        if (t < off) s[t] += s[t + off];
        __syncthreads();
    }
    if (t == 0) bsums[b] = s[0];
}

__global__ void scanB(const int* __restrict__ bsums, int* __restrict__ boffs,
                      int nb, int* __restrict__ rptr_last) {
    if (threadIdx.x == 0 && blockIdx.x == 0) {
        int run = 0;
        for (int i = 0; i < nb; ++i) { boffs[i] = run; run += bsums[i]; }
        rptr_last[0] = run;
    }
}

__global__ void scanC(const int* __restrict__ cnt, const int* __restrict__ boffs,
                      int* __restrict__ rptr, int* __restrict__ cursor, int n) {
    __shared__ int s[256];
    int b = blockIdx.x, t = threadIdx.x;
    int base = b * 1024 + t * 4;
    int v[4], loc[4];
    int sum = 0;
#pragma unroll
    for (int j = 0; j < 4; ++j) {
        int idx = base + j;
        v[j] = (idx < n) ? cnt[idx] : 0;
        loc[j] = sum;
        sum += v[j];
    }
    s[t] = sum;
    __syncthreads();
    for (int off = 1; off < 256; off <<= 1) {
        int x = (t >= off) ? s[t - off] : 0;
        __syncthreads();
        s[t] += x;
        __syncthreads();
    }
    int excl = s[t] - sum;
    int off0 = boffs[b] + excl;
#pragma unroll
    for (int j = 0; j < 4; ++j) {
        int idx = base + j;
        if (idx < n) { int p = off0 + loc[j]; rptr[idx] = p; cursor[idx] = p; }
    }
}

// append edges into CSR buckets; store row index and RAW edge weight
__global__ void scatter_k(const int* __restrict__ ei, const float* __restrict__ ew,
                          int* __restrict__ cursor,
                          int* __restrict__ srow, float* __restrict__ snorm, int E) {
    int e = blockIdx.x * blockDim.x + threadIdx.x;
    if (e >= E) return;
    int r = ei[e], c = ei[E + e];
    int p = atomicAdd(&cursor[c], 1);
    srow[p] = r;
    snorm[p] = ew[e];  // raw weight; normalized in norm_k
}

// node-parallel weighted degree from contiguous buckets (atomic-free)
__global__ void deg_k(const int* __restrict__ rptr, const float* __restrict__ snorm,
                      float* __restrict__ dinv, int n) {
    int i = blockIdx.x * blockDim.x + threadIdx.x;
    if (i >= n) return;
    int s = rptr[i], e = rptr[i + 1];
    float acc = 0.f;
    for (int p = s; p < e; ++p) acc += snorm[p];
    dinv[i] = 1.0f / sqrtf(acc + 1.0f);
}

// node-parallel in-place normalization: snorm[p] *= dinv[row] * dinv[col]
__global__ void norm_k(const int* __restrict__ rptr, const int* __restrict__ srow,
                       const float* __restrict__ dinv, float* __restrict__ snorm, int n) {
    int i = blockIdx.x * blockDim.x + threadIdx.x;
    if (i >= n) return;
    int s = rptr[i], e = rptr[i + 1];
    float dc = dinv[i];
    for (int p = s; p < e; ++p) snorm[p] = snorm[p] * (dinv[srow[p]] * dc);
}

// ---------------- dense matmul h = x @ w ----------------
template <int DIN, int DOUT>
__global__ __launch_bounds__(256) void matmul_k(const float* __restrict__ x,
                                                const float* __restrict__ w,
                                                float* __restrict__ h, int n) {
    constexpr int RPB = 64;
    constexpr int XS = DIN + 4;
    constexpr int J = DOUT / 16;
    __shared__ float xs[RPB * XS];
    __shared__ float4 ws4[DIN * (DOUT / 4)];
    int t = threadIdx.x;
    int row0 = blockIdx.x * RPB;

    for (int i = t; i < DIN * DOUT / 4; i += 256) ws4[i] = ((const float4*)w)[i];
    for (int i = t; i < RPB * DIN / 4; i += 256) {
        int r = i / (DIN / 4), kq = i % (DIN / 4);
        int gr = row0 + r;
        float4 xv = (gr < n) ? ((const float4*)x)[(size_t)gr * (DIN / 4) + kq]
                             : make_float4(0.f, 0.f, 0.f, 0.f);
        *(float4*)&xs[r * XS + kq * 4] = xv;
    }
    __syncthreads();

    int r = t >> 2, cg = t & 3;
    float4 acc[J];
#pragma unroll
    for (int j = 0; j < J; ++j) acc[j] = make_float4(0.f, 0.f, 0.f, 0.f);

    for (int k = 0; k < DIN; ++k) {
        float xv = xs[r * XS + k];
#pragma unroll
        for (int j = 0; j < J; ++j) {
            float4 wv = ws4[k * (DOUT / 4) + cg + 4 * j];
            acc[j] = fma4(xv, wv, acc[j]);
        }
    }
    int gr = row0 + r;
    if (gr < n) {
#pragma unroll
        for (int j = 0; j < J; ++j)
            ((float4*)h)[(size_t)gr * (DOUT / 4) + cg + 4 * j] = acc[j];
    }
}

// ---------------- fused aggregate + self-loop + bias + BN + ReLU ----------------
template <int D>
__global__ __launch_bounds__(256) void agg_k(const float* __restrict__ h,
                                             const int* __restrict__ rptr,
                                             const int* __restrict__ srow,
                                             const float* __restrict__ snorm,
                                             const float* __restrict__ dinv,
                                             const float* __restrict__ bias,
                                             const float* __restrict__ g,
                                             const float* __restrict__ be,
                                             const float* __restrict__ m,
                                             const float* __restrict__ v,
                                             float* __restrict__ y, int n) {
    constexpr int TPN = D / 4;
    int npb = 256 / TPN;
    int node = blockIdx.x * npb + (int)(threadIdx.x / TPN);
    int lc = (int)(threadIdx.x % TPN);
    if (node >= n) return;

    int s = rptr[node], e = rptr[node + 1];
    float4 acc = make_float4(0.f, 0.f, 0.f, 0.f);
    for (int i = s; i < e; ++i) {
        int r = srow[i];
        float wv = snorm[i];
        float4 hv = ((const float4*)h)[(size_t)r * TPN + lc];
        acc = fma4(wv, hv, acc);
    }
    float dv = dinv[node];
    float sn = dv * dv;
    float4 hs = ((const float4*)h)[(size_t)node * TPN + lc];
    float4 bb = ((const float4*)bias)[lc];
    float4 gg = ((const float4*)g)[lc];
    float4 ee = ((const float4*)be)[lc];
    float4 mm = ((const float4*)m)[lc];
    float4 vv = ((const float4*)v)[lc];

    float4 o;
    o.x = acc.x + sn * hs.x + bb.x;
    o.y = acc.y + sn * hs.y + bb.y;
    o.z = acc.z + sn * hs.z + bb.z;
    o.w = acc.w + sn * hs.w + bb.w;

    float4 res;
    res.x = fmaxf((o.x - mm.x) * (gg.x / sqrtf(vv.x + BN_EPS)) + ee.x, 0.f);
    res.y = fmaxf((o.y - mm.y) * (gg.y / sqrtf(vv.y + BN_EPS)) + ee.y, 0.f);
    res.z = fmaxf((o.z - mm.z) * (gg.z / sqrtf(vv.z + BN_EPS)) + ee.z, 0.f);
    res.w = fmaxf((o.w - mm.w) * (gg.w / sqrtf(vv.w + BN_EPS)) + ee.w, 0.f);

    ((float4*)y)[(size_t)node * TPN + lc] = res;
}

// ---------------- parallel global mean pool (batch sorted) ----------------
__global__ __launch_bounds__(256) void pool2_k(const float* __restrict__ y,
                                               const int* __restrict__ batch,
                                               float* __restrict__ sums, int n) {
    const int NPB = 256;
    int node0 = blockIdx.x * NPB;
    int lc = threadIdx.x & 31;
    int nr = threadIdx.x >> 5;
    int end = node0 + NPB < n ? node0 + NPB : n;

    float4 acc = make_float4(0.f, 0.f, 0.f, 0.f);
    int curg = -1;
    for (int i = node0 + nr; i < end; i += 8) {
        int gph = batch[i];
        if (gph != curg) {
            if (curg >= 0) {
                float* dst = &sums[curg * 128 + lc * 4];
                atomicAdd(dst + 0, acc.x);
                atomicAdd(dst + 1, acc.y);
                atomicAdd(dst + 2, acc.z);
                atomicAdd(dst + 3, acc.w);
            }
            acc = make_float4(0.f, 0.f, 0.f, 0.f);
            curg = gph;
        }
        float4 hv = ((const float4*)y)[(size_t)i * 32 + lc];
        acc.x += hv.x; acc.y += hv.y; acc.z += hv.z; acc.w += hv.w;
    }
    if (curg >= 0) {
        float* dst = &sums[curg * 128 + lc * 4];
        atomicAdd(dst + 0, acc.x);
        atomicAdd(dst + 1, acc.y);
        atomicAdd(dst + 2, acc.z);
        atomicAdd(dst + 3, acc.w);
    }
}

__global__ void gcnt_k(const int* __restrict__ batch, float* __restrict__ rcnt, int n) {
    int gph = threadIdx.x;
    if (gph >= 64) return;
    int lo = 0, hi = n;
    while (lo < hi) { int mid = (lo + hi) >> 1; if (batch[mid] < gph) lo = mid + 1; else hi = mid; }
    int s = lo;
    lo = 0; hi = n;
    while (lo < hi) { int mid = (lo + hi) >> 1; if (batch[mid] < gph + 1) lo = mid + 1; else hi = mid; }
    int c = lo - s;
    rcnt[gph] = 1.0f / (c > 0 ? (float)c : 1.0f);
}

// ---------------- final FCs (tiny) ----------------
__global__ __launch_bounds__(256) void fc_k(const float* __restrict__ sums,
                                            const float* __restrict__ rcnt,
                                            const float* __restrict__ fcw,
                                            const float* __restrict__ fcb,
                                            const float* __restrict__ ow,
                                            const float* __restrict__ ob,
                                            float* __restrict__ out) {
    __shared__ float ps[64 * 128];
    __shared__ float hs[64 * 64];
    int t = threadIdx.x;
    for (int i = t; i < 64 * 128; i += 256) ps[i] = sums[i] * rcnt[i >> 7];
    __syncthreads();
    for (int idx = t; idx < 64 * 64; idx += 256) {
        int gph = idx >> 6, j = idx & 63;
        float a = fcb[j];
        for (int k = 0; k < 128; ++k) a = fmaf(ps[gph * 128 + k], fcw[k * 64 + j], a);
        hs[idx] = fmaxf(a, 0.f);
    }
    __syncthreads();
    if (t < 64) {
        float a = ob[0];
        for (int j = 0; j < 64; ++j) a = fmaf(hs[t * 64 + j], ow[j], a);
        out[t] = a;
    }
}

extern "C" void kernel_launch(void* const* d_in, const int* in_sizes, int n_in,
                              void* d_out, int out_size, void* d_ws, size_t ws_size,
                              hipStream_t stream) {
    const float* x     = (const float*)d_in[0];
    const int*   ei    = (const int*)d_in[1];
    const float* ew    = (const float*)d_in[2];
    const int*   batch = (const int*)d_in[3];
    const float* w1 = (const float*)d_in[4],  *b1 = (const float*)d_in[5];
    const float* g1 = (const float*)d_in[6],  *be1 = (const float*)d_in[7];
    const float* m1 = (const float*)d_in[8],  *v1 = (const float*)d_in[9];
    const float* w2 = (const float*)d_in[10], *b2 = (const float*)d_in[11];
    const float* g2 = (const float*)d_in[12], *be2 = (const float*)d_in[13];
    const float* m2 = (const float*)d_in[14], *v2 = (const float*)d_in[15];
    const float* w3 = (const float*)d_in[16], *b3 = (const float*)d_in[17];
    const float* g3 = (const float*)d_in[18], *be3 = (const float*)d_in[19];
    const float* m3 = (const float*)d_in[20], *v3 = (const float*)d_in[21];
    const float* fcw = (const float*)d_in[22], *fcb = (const float*)d_in[23];
    const float* ow  = (const float*)d_in[24], *ob  = (const float*)d_in[25];
    float* out = (float*)d_out;

    const int N = in_sizes[3];
    const int E = in_sizes[2];

    // workspace layout
    float* A    = (float*)d_ws;            // N x 128
    float* Bf   = A + (size_t)N * 128;     // N x 128
    float* dinv = Bf + (size_t)N * 128;    // N
    int*   cnt    = (int*)(dinv + N);      // N
    int*   rptr   = cnt + N;               // N+1
    int*   cursor = rptr + (N + 1);        // N
    int*   bsums  = cursor + N;            // 1024
    int*   boffs  = bsums + 1024;          // 1024
    int*   srow   = boffs + 1024;          // E
    float* snorm  = (float*)(srow + E);    // E (raw ew, then normalized in place)
    float* sums   = snorm + E;             // 64*128
    float* rcnt   = sums + 64 * 128;       // 64

    hipMemsetAsync(cnt, 0, (size_t)N * sizeof(int), stream);
    hipMemsetAsync(sums, 0, 64 * 128 * sizeof(float), stream);

    int eb = (E + 255) / 256;
    int nb = (N + 255) / 256;
    int nsb = (N + 1023) / 1024;

    hist_k<<<eb, 256, 0, stream>>>(ei, cnt, E);
    scanA<<<nsb, 256, 0, stream>>>(cnt, bsums, N);
    scanB<<<1, 64, 0, stream>>>(bsums, boffs, nsb, rptr + N);
    scanC<<<nsb, 256, 0, stream>>>(cnt, boffs, rptr, cursor, N);
    scatter_k<<<eb, 256, 0, stream>>>(ei, ew, cursor, srow, snorm, E);
    deg_k<<<nb, 256, 0, stream>>>(rptr, snorm, dinv, N);
    norm_k<<<nb, 256, 0, stream>>>(rptr, srow, dinv, snorm, N);

    matmul_k<64, 32><<<(N + 63) / 64, 256, 0, stream>>>(x, w1, A, N);
    agg_k<32><<<(N + 31) / 32, 256, 0, stream>>>(A, rptr, srow, snorm, dinv,
                                                 b1, g1, be1, m1, v1, Bf, N);
    matmul_k<32, 64><<<(N + 63) / 64, 256, 0, stream>>>(Bf, w2, A, N);
    agg_k<64><<<(N + 15) / 16, 256, 0, stream>>>(A, rptr, srow, snorm, dinv,
                                                 b2, g2, be2, m2, v2, Bf, N);
    matmul_k<64, 128><<<(N + 63) / 64, 256, 0, stream>>>(Bf, w3, A, N);
    agg_k<128><<<(N + 7) / 8, 256, 0, stream>>>(A, rptr, srow, snorm, dinv,
                                                b3, g3, be3, m3, v3, Bf, N);

    pool2_k<<<(N + 255) / 256, 256, 0, stream>>>(Bf, batch, sums, N);
    gcnt_k<<<1, 64, 0, stream>>>(batch, rcnt, N);
    fc_k<<<1, 256, 0, stream>>>(sums, rcnt, fcw, fcb, ow, ob, out);
}

// Round 4
// 519.568 us; speedup vs baseline: 1.9382x; 1.1581x over previous
//
#include <hip/hip_runtime.h>
#include <math.h>

#define BN_EPS 1e-5f

__device__ __forceinline__ float4 fma4(float s, float4 a, float4 b) {
    return make_float4(fmaf(s, a.x, b.x), fmaf(s, a.y, b.y),
                       fmaf(s, a.z, b.z), fmaf(s, a.w, b.w));
}

// ---------------- degree / CSR preprocessing ----------------

__global__ void hist_k(const int* __restrict__ ei, int* __restrict__ cnt, int E) {
    int e = blockIdx.x * blockDim.x + threadIdx.x;
    if (e >= E) return;
    atomicAdd(&cnt[ei[E + e]], 1);
}

__global__ void scanA(const int* __restrict__ cnt, int* __restrict__ bsums, int n) {
    __shared__ int s[256];
    int b = blockIdx.x, t = threadIdx.x;
    int base = b * 1024 + t * 4;
    int sum = 0;
#pragma unroll
    for (int j = 0; j < 4; ++j) { int idx = base + j; if (idx < n) sum += cnt[idx]; }
    s[t] = sum;
    __syncthreads();
    for (int off = 128; off > 0; off >>= 1) {
        if (t < off) s[t] += s[t + off];
        __syncthreads();
    }
    if (t == 0) bsums[b] = s[0];
}

__global__ void scanB(const int* __restrict__ bsums, int* __restrict__ boffs,
                      int nb, int* __restrict__ rptr_last) {
    if (threadIdx.x == 0 && blockIdx.x == 0) {
        int run = 0;
        for (int i = 0; i < nb; ++i) { boffs[i] = run; run += bsums[i]; }
        rptr_last[0] = run;
    }
}

__global__ void scanC(const int* __restrict__ cnt, const int* __restrict__ boffs,
                      int* __restrict__ rptr, int* __restrict__ cursor, int n) {
    __shared__ int s[256];
    int b = blockIdx.x, t = threadIdx.x;
    int base = b * 1024 + t * 4;
    int v[4], loc[4];
    int sum = 0;
#pragma unroll
    for (int j = 0; j < 4; ++j) {
        int idx = base + j;
        v[j] = (idx < n) ? cnt[idx] : 0;
        loc[j] = sum;
        sum += v[j];
    }
    s[t] = sum;
    __syncthreads();
    for (int off = 1; off < 256; off <<= 1) {
        int x = (t >= off) ? s[t - off] : 0;
        __syncthreads();
        s[t] += x;
        __syncthreads();
    }
    int excl = s[t] - sum;
    int off0 = boffs[b] + excl;
#pragma unroll
    for (int j = 0; j < 4; ++j) {
        int idx = base + j;
        if (idx < n) { int p = off0 + loc[j]; rptr[idx] = p; cursor[idx] = p; }
    }
}

__global__ void scatter_k(const int* __restrict__ ei, const float* __restrict__ ew,
                          int* __restrict__ cursor,
                          int* __restrict__ srow, float* __restrict__ snorm, int E) {
    int e = blockIdx.x * blockDim.x + threadIdx.x;
    if (e >= E) return;
    int r = ei[e], c = ei[E + e];
    int p = atomicAdd(&cursor[c], 1);
    srow[p] = r;
    snorm[p] = ew[e];
}

__global__ void deg_k(const int* __restrict__ rptr, const float* __restrict__ snorm,
                      float* __restrict__ dinv, int n) {
    int i = blockIdx.x * blockDim.x + threadIdx.x;
    if (i >= n) return;
    int s = rptr[i], e = rptr[i + 1];
    float acc = 0.f;
    for (int p = s; p < e; ++p) acc += snorm[p];
    dinv[i] = 1.0f / sqrtf(acc + 1.0f);
}

__global__ void norm_k(const int* __restrict__ rptr, const int* __restrict__ srow,
                       const float* __restrict__ dinv, float* __restrict__ snorm, int n) {
    int i = blockIdx.x * blockDim.x + threadIdx.x;
    if (i >= n) return;
    int s = rptr[i], e = rptr[i + 1];
    float dc = dinv[i];
    for (int p = s; p < e; ++p) snorm[p] = snorm[p] * (dinv[srow[p]] * dc);
}

// ---------------- dense matmul h = x @ w (plain) ----------------
template <int DIN, int DOUT>
__global__ __launch_bounds__(256) void matmul_k(const float* __restrict__ x,
                                                const float* __restrict__ w,
                                                float* __restrict__ h, int n) {
    constexpr int RPB = 64;
    constexpr int XS = DIN + 4;
    constexpr int J = DOUT / 16;
    __shared__ float xs[RPB * XS];
    __shared__ float4 ws4[DIN * (DOUT / 4)];
    int t = threadIdx.x;
    int row0 = blockIdx.x * RPB;

    for (int i = t; i < DIN * DOUT / 4; i += 256) ws4[i] = ((const float4*)w)[i];
    for (int i = t; i < RPB * DIN / 4; i += 256) {
        int r = i / (DIN / 4), kq = i % (DIN / 4);
        int gr = row0 + r;
        float4 xv = (gr < n) ? ((const float4*)x)[(size_t)gr * (DIN / 4) + kq]
                             : make_float4(0.f, 0.f, 0.f, 0.f);
        *(float4*)&xs[r * XS + kq * 4] = xv;
    }
    __syncthreads();

    int r = t >> 2, cg = t & 3;
    float4 acc[J];
#pragma unroll
    for (int j = 0; j < J; ++j) acc[j] = make_float4(0.f, 0.f, 0.f, 0.f);

    for (int k = 0; k < DIN; ++k) {
        float xv = xs[r * XS + k];
#pragma unroll
        for (int j = 0; j < J; ++j) {
            float4 wv = ws4[k * (DOUT / 4) + cg + 4 * j];
            acc[j] = fma4(xv, wv, acc[j]);
        }
    }
    int gr = row0 + r;
    if (gr < n) {
#pragma unroll
        for (int j = 0; j < J; ++j)
            ((float4*)h)[(size_t)gr * (DOUT / 4) + cg + 4 * j] = acc[j];
    }
}

// ---------------- dense matmul with fused bias + BN + ReLU epilogue ----------------
template <int DIN, int DOUT>
__global__ __launch_bounds__(256) void matmulBN_k(const float* __restrict__ x,
                                                  const float* __restrict__ w,
                                                  const float* __restrict__ bias,
                                                  const float* __restrict__ g,
                                                  const float* __restrict__ be,
                                                  const float* __restrict__ m,
                                                  const float* __restrict__ v,
                                                  float* __restrict__ h, int n) {
    constexpr int RPB = 64;
    constexpr int XS = DIN + 4;
    constexpr int J = DOUT / 16;
    __shared__ float xs[RPB * XS];
    __shared__ float4 ws4[DIN * (DOUT / 4)];
    int t = threadIdx.x;
    int row0 = blockIdx.x * RPB;

    for (int i = t; i < DIN * DOUT / 4; i += 256) ws4[i] = ((const float4*)w)[i];
    for (int i = t; i < RPB * DIN / 4; i += 256) {
        int r = i / (DIN / 4), kq = i % (DIN / 4);
        int gr = row0 + r;
        float4 xv = (gr < n) ? ((const float4*)x)[(size_t)gr * (DIN / 4) + kq]
                             : make_float4(0.f, 0.f, 0.f, 0.f);
        *(float4*)&xs[r * XS + kq * 4] = xv;
    }
    __syncthreads();

    int r = t >> 2, cg = t & 3;
    float4 acc[J];
#pragma unroll
    for (int j = 0; j < J; ++j) acc[j] = make_float4(0.f, 0.f, 0.f, 0.f);

    for (int k = 0; k < DIN; ++k) {
        float xv = xs[r * XS + k];
#pragma unroll
        for (int j = 0; j < J; ++j) {
            float4 wv = ws4[k * (DOUT / 4) + cg + 4 * j];
            acc[j] = fma4(xv, wv, acc[j]);
        }
    }
    int gr = row0 + r;
    if (gr < n) {
#pragma unroll
        for (int j = 0; j < J; ++j) {
            int c4 = cg + 4 * j;
            float4 bb = ((const float4*)bias)[c4];
            float4 gg = ((const float4*)g)[c4];
            float4 ee = ((const float4*)be)[c4];
            float4 mm = ((const float4*)m)[c4];
            float4 vv = ((const float4*)v)[c4];
            float4 o = acc[j];
            float4 res;
            res.x = fmaxf((o.x + bb.x - mm.x) * (gg.x / sqrtf(vv.x + BN_EPS)) + ee.x, 0.f);
            res.y = fmaxf((o.y + bb.y - mm.y) * (gg.y / sqrtf(vv.y + BN_EPS)) + ee.y, 0.f);
            res.z = fmaxf((o.z + bb.z - mm.z) * (gg.z / sqrtf(vv.z + BN_EPS)) + ee.z, 0.f);
            res.w = fmaxf((o.w + bb.w - mm.w) * (gg.w / sqrtf(vv.w + BN_EPS)) + ee.w, 0.f);
            ((float4*)h)[(size_t)gr * (DOUT / 4) + c4] = res;
        }
    }
}

// ---------------- aggregate AFTER matmul, fused bias+BN+ReLU (layer 1) ----------------
template <int D>
__global__ __launch_bounds__(256) void agg_k(const float* __restrict__ h,
                                             const int* __restrict__ rptr,
                                             const int* __restrict__ srow,
                                             const float* __restrict__ snorm,
                                             const float* __restrict__ dinv,
                                             const float* __restrict__ bias,
                                             const float* __restrict__ g,
                                             const float* __restrict__ be,
                                             const float* __restrict__ m,
                                             const float* __restrict__ v,
                                             float* __restrict__ y, int n) {
    constexpr int TPN = D / 4;
    int npb = 256 / TPN;
    int node = blockIdx.x * npb + (int)(threadIdx.x / TPN);
    int lc = (int)(threadIdx.x % TPN);
    if (node >= n) return;

    int s = rptr[node], e = rptr[node + 1];
    float4 acc = make_float4(0.f, 0.f, 0.f, 0.f);
    for (int i = s; i < e; ++i) {
        int r = srow[i];
        float wv = snorm[i];
        float4 hv = ((const float4*)h)[(size_t)r * TPN + lc];
        acc = fma4(wv, hv, acc);
    }
    float dv = dinv[node];
    float sn = dv * dv;
    float4 hs = ((const float4*)h)[(size_t)node * TPN + lc];
    float4 bb = ((const float4*)bias)[lc];
    float4 gg = ((const float4*)g)[lc];
    float4 ee = ((const float4*)be)[lc];
    float4 mm = ((const float4*)m)[lc];
    float4 vv = ((const float4*)v)[lc];

    float4 o;
    o.x = acc.x + sn * hs.x + bb.x;
    o.y = acc.y + sn * hs.y + bb.y;
    o.z = acc.z + sn * hs.z + bb.z;
    o.w = acc.w + sn * hs.w + bb.w;

    float4 res;
    res.x = fmaxf((o.x - mm.x) * (gg.x / sqrtf(vv.x + BN_EPS)) + ee.x, 0.f);
    res.y = fmaxf((o.y - mm.y) * (gg.y / sqrtf(vv.y + BN_EPS)) + ee.y, 0.f);
    res.z = fmaxf((o.z - mm.z) * (gg.z / sqrtf(vv.z + BN_EPS)) + ee.z, 0.f);
    res.w = fmaxf((o.w - mm.w) * (gg.w / sqrtf(vv.w + BN_EPS)) + ee.w, 0.f);

    ((float4*)y)[(size_t)node * TPN + lc] = res;
}

// ---------------- aggregate BEFORE matmul: z = agg + self_norm * y_in ----------------
template <int D>
__global__ __launch_bounds__(256) void aggpre_k(const float* __restrict__ h,
                                                const int* __restrict__ rptr,
                                                const int* __restrict__ srow,
                                                const float* __restrict__ snorm,
                                                const float* __restrict__ dinv,
                                                float* __restrict__ z, int n) {
    constexpr int TPN = D / 4;
    int npb = 256 / TPN;
    int node = blockIdx.x * npb + (int)(threadIdx.x / TPN);
    int lc = (int)(threadIdx.x % TPN);
    if (node >= n) return;

    int s = rptr[node], e = rptr[node + 1];
    float4 acc = make_float4(0.f, 0.f, 0.f, 0.f);
    for (int i = s; i < e; ++i) {
        int r = srow[i];
        float wv = snorm[i];
        float4 hv = ((const float4*)h)[(size_t)r * TPN + lc];
        acc = fma4(wv, hv, acc);
    }
    float dv = dinv[node];
    float sn = dv * dv;
    float4 hs = ((const float4*)h)[(size_t)node * TPN + lc];
    acc.x = fmaf(sn, hs.x, acc.x);
    acc.y = fmaf(sn, hs.y, acc.y);
    acc.z = fmaf(sn, hs.z, acc.z);
    acc.w = fmaf(sn, hs.w, acc.w);
    ((float4*)z)[(size_t)node * TPN + lc] = acc;
}

// ---------------- parallel global mean pool (batch sorted) ----------------
__global__ __launch_bounds__(256) void pool2_k(const float* __restrict__ y,
                                               const int* __restrict__ batch,
                                               float* __restrict__ sums, int n) {
    const int NPB = 256;
    int node0 = blockIdx.x * NPB;
    int lc = threadIdx.x & 31;
    int nr = threadIdx.x >> 5;
    int end = node0 + NPB < n ? node0 + NPB : n;

    float4 acc = make_float4(0.f, 0.f, 0.f, 0.f);
    int curg = -1;
    for (int i = node0 + nr; i < end; i += 8) {
        int gph = batch[i];
        if (gph != curg) {
            if (curg >= 0) {
                float* dst = &sums[curg * 128 + lc * 4];
                atomicAdd(dst + 0, acc.x);
                atomicAdd(dst + 1, acc.y);
                atomicAdd(dst + 2, acc.z);
                atomicAdd(dst + 3, acc.w);
            }
            acc = make_float4(0.f, 0.f, 0.f, 0.f);
            curg = gph;
        }
        float4 hv = ((const float4*)y)[(size_t)i * 32 + lc];
        acc.x += hv.x; acc.y += hv.y; acc.z += hv.z; acc.w += hv.w;
    }
    if (curg >= 0) {
        float* dst = &sums[curg * 128 + lc * 4];
        atomicAdd(dst + 0, acc.x);
        atomicAdd(dst + 1, acc.y);
        atomicAdd(dst + 2, acc.z);
        atomicAdd(dst + 3, acc.w);
    }
}

__global__ void gcnt_k(const int* __restrict__ batch, float* __restrict__ rcnt, int n) {
    int gph = threadIdx.x;
    if (gph >= 64) return;
    int lo = 0, hi = n;
    while (lo < hi) { int mid = (lo + hi) >> 1; if (batch[mid] < gph) lo = mid + 1; else hi = mid; }
    int s = lo;
    lo = 0; hi = n;
    while (lo < hi) { int mid = (lo + hi) >> 1; if (batch[mid] < gph + 1) lo = mid + 1; else hi = mid; }
    int c = lo - s;
    rcnt[gph] = 1.0f / (c > 0 ? (float)c : 1.0f);
}

// ---------------- final FCs (tiny) ----------------
__global__ __launch_bounds__(256) void fc_k(const float* __restrict__ sums,
                                            const float* __restrict__ rcnt,
                                            const float* __restrict__ fcw,
                                            const float* __restrict__ fcb,
                                            const float* __restrict__ ow,
                                            const float* __restrict__ ob,
                                            float* __restrict__ out) {
    __shared__ float ps[64 * 128];
    __shared__ float hs[64 * 64];
    int t = threadIdx.x;
    for (int i = t; i < 64 * 128; i += 256) ps[i] = sums[i] * rcnt[i >> 7];
    __syncthreads();
    for (int idx = t; idx < 64 * 64; idx += 256) {
        int gph = idx >> 6, j = idx & 63;
        float a = fcb[j];
        for (int k = 0; k < 128; ++k) a = fmaf(ps[gph * 128 + k], fcw[k * 64 + j], a);
        hs[idx] = fmaxf(a, 0.f);
    }
    __syncthreads();
    if (t < 64) {
        float a = ob[0];
        for (int j = 0; j < 64; ++j) a = fmaf(hs[t * 64 + j], ow[j], a);
        out[t] = a;
    }
}

extern "C" void kernel_launch(void* const* d_in, const int* in_sizes, int n_in,
                              void* d_out, int out_size, void* d_ws, size_t ws_size,
                              hipStream_t stream) {
    const float* x     = (const float*)d_in[0];
    const int*   ei    = (const int*)d_in[1];
    const float* ew    = (const float*)d_in[2];
    const int*   batch = (const int*)d_in[3];
    const float* w1 = (const float*)d_in[4],  *b1 = (const float*)d_in[5];
    const float* g1 = (const float*)d_in[6],  *be1 = (const float*)d_in[7];
    const float* m1 = (const float*)d_in[8],  *v1 = (const float*)d_in[9];
    const float* w2 = (const float*)d_in[10], *b2 = (const float*)d_in[11];
    const float* g2 = (const float*)d_in[12], *be2 = (const float*)d_in[13];
    const float* m2 = (const float*)d_in[14], *v2 = (const float*)d_in[15];
    const float* w3 = (const float*)d_in[16], *b3 = (const float*)d_in[17];
    const float* g3 = (const float*)d_in[18], *be3 = (const float*)d_in[19];
    const float* m3 = (const float*)d_in[20], *v3 = (const float*)d_in[21];
    const float* fcw = (const float*)d_in[22], *fcb = (const float*)d_in[23];
    const float* ow  = (const float*)d_in[24], *ob  = (const float*)d_in[25];
    float* out = (float*)d_out;

    const int N = in_sizes[3];
    const int E = in_sizes[2];

    // workspace layout
    float* A    = (float*)d_ws;            // N x 128
    float* Bf   = A + (size_t)N * 128;     // N x 128
    float* dinv = Bf + (size_t)N * 128;    // N
    int*   cnt    = (int*)(dinv + N);      // N
    int*   rptr   = cnt + N;               // N+1
    int*   cursor = rptr + (N + 1);        // N
    int*   bsums  = cursor + N;            // 1024
    int*   boffs  = bsums + 1024;          // 1024
    int*   srow   = boffs + 1024;          // E
    float* snorm  = (float*)(srow + E);    // E
    float* sums   = snorm + E;             // 64*128
    float* rcnt   = sums + 64 * 128;       // 64

    hipMemsetAsync(cnt, 0, (size_t)N * sizeof(int), stream);
    hipMemsetAsync(sums, 0, 64 * 128 * sizeof(float), stream);

    int eb = (E + 255) / 256;
    int nb = (N + 255) / 256;
    int nsb = (N + 1023) / 1024;

    hist_k<<<eb, 256, 0, stream>>>(ei, cnt, E);
    scanA<<<nsb, 256, 0, stream>>>(cnt, bsums, N);
    scanB<<<1, 64, 0, stream>>>(bsums, boffs, nsb, rptr + N);
    scanC<<<nsb, 256, 0, stream>>>(cnt, boffs, rptr, cursor, N);
    scatter_k<<<eb, 256, 0, stream>>>(ei, ew, cursor, srow, snorm, E);
    deg_k<<<nb, 256, 0, stream>>>(rptr, snorm, dinv, N);
    norm_k<<<nb, 256, 0, stream>>>(rptr, srow, dinv, snorm, N);

    // layer 1: matmul 64->32, then aggregate in 32-dim with BN/ReLU epilogue
    matmul_k<64, 32><<<(N + 63) / 64, 256, 0, stream>>>(x, w1, A, N);
    agg_k<32><<<(N + 31) / 32, 256, 0, stream>>>(A, rptr, srow, snorm, dinv,
                                                 b1, g1, be1, m1, v1, Bf, N);
    // layer 2: aggregate in 32-dim, then matmul 32->64 with fused bias/BN/ReLU
    aggpre_k<32><<<(N + 31) / 32, 256, 0, stream>>>(Bf, rptr, srow, snorm, dinv, A, N);
    matmulBN_k<32, 64><<<(N + 63) / 64, 256, 0, stream>>>(A, w2, b2, g2, be2, m2, v2, Bf, N);
    // layer 3: aggregate in 64-dim, then matmul 64->128 with fused bias/BN/ReLU
    aggpre_k<64><<<(N + 15) / 16, 256, 0, stream>>>(Bf, rptr, srow, snorm, dinv, A, N);
    matmulBN_k<64, 128><<<(N + 63) / 64, 256, 0, stream>>>(A, w3, b3, g3, be3, m3, v3, Bf, N);

    pool2_k<<<(N + 255) / 256, 256, 0, stream>>>(Bf, batch, sums, N);
    gcnt_k<<<1, 64, 0, stream>>>(batch, rcnt, N);
    fc_k<<<1, 256, 0, stream>>>(sums, rcnt, fcw, fcb, ow, ob, out);
}

// Round 5
// 392.185 us; speedup vs baseline: 2.5677x; 1.3248x over previous
//
#include <hip/hip_runtime.h>
#include <math.h>

#define BN_EPS 1e-5f
#define NBSH 7          // 128 nodes per coarse bucket
#define BKT 128

__device__ __forceinline__ float4 fma4(float s, float4 a, float4 b) {
    return make_float4(fmaf(s, a.x, b.x), fmaf(s, a.y, b.y),
                       fmaf(s, a.z, b.z), fmaf(s, a.w, b.w));
}

// ---------------- two-level counting sort: CSR by col ----------------

// coarse histogram of col>>7 with LDS privatization
__global__ __launch_bounds__(256) void chist_k(const int* __restrict__ ei,
                                               int* __restrict__ chist, int E, int NB) {
    __shared__ int h[1024];
    int t = threadIdx.x;
    for (int i = t; i < NB; i += 256) h[i] = 0;
    __syncthreads();
    for (int e = blockIdx.x * 256 + t; e < E; e += gridDim.x * 256)
        atomicAdd(&h[((unsigned)ei[E + e]) >> NBSH], 1);
    __syncthreads();
    for (int i = t; i < NB; i += 256) if (h[i]) atomicAdd(&chist[i], h[i]);
}

// one-block scan -> cbase[0..NB], ccur copy; also rptr[N] = E
__global__ __launch_bounds__(1024) void cscan_k(const int* __restrict__ chist,
                                                int* __restrict__ cbase,
                                                int* __restrict__ ccur,
                                                int NB, int* __restrict__ rptrN, int E) {
    __shared__ int s[1024];
    int t = threadIdx.x;
    int v = (t < NB) ? chist[t] : 0;
    s[t] = v;
    __syncthreads();
    for (int off = 1; off < 1024; off <<= 1) {
        int x = (t >= off) ? s[t - off] : 0;
        __syncthreads();
        s[t] += x;
        __syncthreads();
    }
    int excl = s[t] - v;
    if (t < NB) { cbase[t] = excl; ccur[t] = excl; }
    if (t == 0) { cbase[NB] = E; rptrN[0] = E; }
}

// coarse scatter: group edges by bucket, pack {row | cib<<17, raw w}
__global__ __launch_bounds__(256) void cscat_k(const int* __restrict__ ei,
                                               const float* __restrict__ ew,
                                               int* __restrict__ ccur,
                                               int2* __restrict__ pairs0, int E, int NB) {
    __shared__ int h[1024];
    __shared__ int base[1024];
    int t = threadIdx.x;
    int CH = (E + gridDim.x - 1) / gridDim.x;
    int lo = blockIdx.x * CH;
    int hi = lo + CH < E ? lo + CH : E;

    for (int i = t; i < NB; i += 256) h[i] = 0;
    __syncthreads();
    for (int e = lo + t; e < hi; e += 256)
        atomicAdd(&h[((unsigned)ei[E + e]) >> NBSH], 1);
    __syncthreads();
    for (int i = t; i < NB; i += 256) {
        int c = h[i];
        base[i] = c ? atomicAdd(&ccur[i], c) : 0;
        h[i] = 0;  // reuse as local cursor
    }
    __syncthreads();
    for (int e = lo + t; e < hi; e += 256) {
        int c = ei[E + e];
        int b = ((unsigned)c) >> NBSH;
        int idx = base[b] + atomicAdd(&h[b], 1);
        pairs0[idx] = make_int2(ei[e] | ((c & (BKT - 1)) << 17), __float_as_int(ew[e]));
    }
}

// fine pass A: per-bucket node histogram + weighted degree -> rptr, dinv
__global__ __launch_bounds__(BKT) void fineA_k(const int2* __restrict__ pairs0,
                                               const int* __restrict__ cbase,
                                               int* __restrict__ rptr,
                                               float* __restrict__ dinv, int N) {
    int b = blockIdx.x;
    __shared__ int cnt[BKT];
    __shared__ float wsum[BKT];
    __shared__ int sc[BKT];
    int t = threadIdx.x;
    cnt[t] = 0; wsum[t] = 0.f;
    __syncthreads();
    int s = cbase[b], e = cbase[b + 1];
    for (int i = s + t; i < e; i += BKT) {
        int2 p = pairs0[i];
        int cib = ((unsigned)p.x) >> 17;
        atomicAdd(&cnt[cib], 1);
        atomicAdd(&wsum[cib], __int_as_float(p.y));
    }
    __syncthreads();
    int v = cnt[t];
    sc[t] = v;
    __syncthreads();
    for (int off = 1; off < BKT; off <<= 1) {
        int x = (t >= off) ? sc[t - off] : 0;
        __syncthreads();
        sc[t] += x;
        __syncthreads();
    }
    int node = b * BKT + t;
    if (node < N) {
        rptr[node] = s + sc[t] - v;
        dinv[node] = 1.0f / sqrtf(wsum[t] + 1.0f);
    }
}

// fine pass B: scatter into final CSR with full normalization applied
__global__ __launch_bounds__(BKT) void fineB_k(const int2* __restrict__ pairs0,
                                               const int* __restrict__ cbase,
                                               const int* __restrict__ rptr,
                                               const float* __restrict__ dinv,
                                               int2* __restrict__ pairs, int N) {
    int b = blockIdx.x;
    __shared__ int cur[BKT];
    __shared__ float dc[BKT];
    int t = threadIdx.x;
    int node = b * BKT + t;
    cur[t] = (node < N) ? rptr[node] : 0;
    dc[t] = (node < N) ? dinv[node] : 0.f;
    __syncthreads();
    int s = cbase[b], e = cbase[b + 1];
    for (int i = s + t; i < e; i += BKT) {
        int2 p = pairs0[i];
        int cib = ((unsigned)p.x) >> 17;
        int row = p.x & 0x1FFFF;
        float nw = dinv[row] * __int_as_float(p.y) * dc[cib];
        int pos = atomicAdd(&cur[cib], 1);
        pairs[pos] = make_int2(row, __float_as_int(nw));
    }
}

// ---------------- dense matmul h = x @ w (plain) ----------------
template <int DIN, int DOUT>
__global__ __launch_bounds__(256) void matmul_k(const float* __restrict__ x,
                                                const float* __restrict__ w,
                                                float* __restrict__ h, int n) {
    constexpr int RPB = 64;
    constexpr int XS = DIN + 4;
    constexpr int J = DOUT / 16;
    __shared__ float xs[RPB * XS];
    __shared__ float4 ws4[DIN * (DOUT / 4)];
    int t = threadIdx.x;
    int row0 = blockIdx.x * RPB;

    for (int i = t; i < DIN * DOUT / 4; i += 256) ws4[i] = ((const float4*)w)[i];
    for (int i = t; i < RPB * DIN / 4; i += 256) {
        int r = i / (DIN / 4), kq = i % (DIN / 4);
        int gr = row0 + r;
        float4 xv = (gr < n) ? ((const float4*)x)[(size_t)gr * (DIN / 4) + kq]
                             : make_float4(0.f, 0.f, 0.f, 0.f);
        *(float4*)&xs[r * XS + kq * 4] = xv;
    }
    __syncthreads();

    int r = t >> 2, cg = t & 3;
    float4 acc[J];
#pragma unroll
    for (int j = 0; j < J; ++j) acc[j] = make_float4(0.f, 0.f, 0.f, 0.f);

    for (int k = 0; k < DIN; ++k) {
        float xv = xs[r * XS + k];
#pragma unroll
        for (int j = 0; j < J; ++j) {
            float4 wv = ws4[k * (DOUT / 4) + cg + 4 * j];
            acc[j] = fma4(xv, wv, acc[j]);
        }
    }
    int gr = row0 + r;
    if (gr < n) {
#pragma unroll
        for (int j = 0; j < J; ++j)
            ((float4*)h)[(size_t)gr * (DOUT / 4) + cg + 4 * j] = acc[j];
    }
}

// ---------------- dense matmul with fused bias + BN + ReLU epilogue ----------------
template <int DIN, int DOUT>
__global__ __launch_bounds__(256) void matmulBN_k(const float* __restrict__ x,
                                                  const float* __restrict__ w,
                                                  const float* __restrict__ bias,
                                                  const float* __restrict__ g,
                                                  const float* __restrict__ be,
                                                  const float* __restrict__ m,
                                                  const float* __restrict__ v,
                                                  float* __restrict__ h, int n) {
    constexpr int RPB = 64;
    constexpr int XS = DIN + 4;
    constexpr int J = DOUT / 16;
    __shared__ float xs[RPB * XS];
    __shared__ float4 ws4[DIN * (DOUT / 4)];
    int t = threadIdx.x;
    int row0 = blockIdx.x * RPB;

    for (int i = t; i < DIN * DOUT / 4; i += 256) ws4[i] = ((const float4*)w)[i];
    for (int i = t; i < RPB * DIN / 4; i += 256) {
        int r = i / (DIN / 4), kq = i % (DIN / 4);
        int gr = row0 + r;
        float4 xv = (gr < n) ? ((const float4*)x)[(size_t)gr * (DIN / 4) + kq]
                             : make_float4(0.f, 0.f, 0.f, 0.f);
        *(float4*)&xs[r * XS + kq * 4] = xv;
    }
    __syncthreads();

    int r = t >> 2, cg = t & 3;
    float4 acc[J];
#pragma unroll
    for (int j = 0; j < J; ++j) acc[j] = make_float4(0.f, 0.f, 0.f, 0.f);

    for (int k = 0; k < DIN; ++k) {
        float xv = xs[r * XS + k];
#pragma unroll
        for (int j = 0; j < J; ++j) {
            float4 wv = ws4[k * (DOUT / 4) + cg + 4 * j];
            acc[j] = fma4(xv, wv, acc[j]);
        }
    }
    int gr = row0 + r;
    if (gr < n) {
#pragma unroll
        for (int j = 0; j < J; ++j) {
            int c4 = cg + 4 * j;
            float4 bb = ((const float4*)bias)[c4];
            float4 gg = ((const float4*)g)[c4];
            float4 ee = ((const float4*)be)[c4];
            float4 mm = ((const float4*)m)[c4];
            float4 vv = ((const float4*)v)[c4];
            float4 o = acc[j];
            float4 res;
            res.x = fmaxf((o.x + bb.x - mm.x) * (gg.x / sqrtf(vv.x + BN_EPS)) + ee.x, 0.f);
            res.y = fmaxf((o.y + bb.y - mm.y) * (gg.y / sqrtf(vv.y + BN_EPS)) + ee.y, 0.f);
            res.z = fmaxf((o.z + bb.z - mm.z) * (gg.z / sqrtf(vv.z + BN_EPS)) + ee.z, 0.f);
            res.w = fmaxf((o.w + bb.w - mm.w) * (gg.w / sqrtf(vv.w + BN_EPS)) + ee.w, 0.f);
            ((float4*)h)[(size_t)gr * (DOUT / 4) + c4] = res;
        }
    }
}

// ---------------- aggregate AFTER matmul, fused bias+BN+ReLU (layer 1) ----------------
template <int D>
__global__ __launch_bounds__(256) void agg_k(const float* __restrict__ h,
                                             const int* __restrict__ rptr,
                                             const int2* __restrict__ pairs,
                                             const float* __restrict__ dinv,
                                             const float* __restrict__ bias,
                                             const float* __restrict__ g,
                                             const float* __restrict__ be,
                                             const float* __restrict__ m,
                                             const float* __restrict__ v,
                                             float* __restrict__ y, int n) {
    constexpr int TPN = D / 4;
    int npb = 256 / TPN;
    int node = blockIdx.x * npb + (int)(threadIdx.x / TPN);
    int lc = (int)(threadIdx.x % TPN);
    if (node >= n) return;

    int s = rptr[node], e = rptr[node + 1];
    float4 acc = make_float4(0.f, 0.f, 0.f, 0.f);
    for (int i = s; i < e; ++i) {
        int2 pr = pairs[i];
        float wv = __int_as_float(pr.y);
        float4 hv = ((const float4*)h)[(size_t)pr.x * TPN + lc];
        acc = fma4(wv, hv, acc);
    }
    float dv = dinv[node];
    float sn = dv * dv;
    float4 hs = ((const float4*)h)[(size_t)node * TPN + lc];
    float4 bb = ((const float4*)bias)[lc];
    float4 gg = ((const float4*)g)[lc];
    float4 ee = ((const float4*)be)[lc];
    float4 mm = ((const float4*)m)[lc];
    float4 vv = ((const float4*)v)[lc];

    float4 o;
    o.x = acc.x + sn * hs.x + bb.x;
    o.y = acc.y + sn * hs.y + bb.y;
    o.z = acc.z + sn * hs.z + bb.z;
    o.w = acc.w + sn * hs.w + bb.w;

    float4 res;
    res.x = fmaxf((o.x - mm.x) * (gg.x / sqrtf(vv.x + BN_EPS)) + ee.x, 0.f);
    res.y = fmaxf((o.y - mm.y) * (gg.y / sqrtf(vv.y + BN_EPS)) + ee.y, 0.f);
    res.z = fmaxf((o.z - mm.z) * (gg.z / sqrtf(vv.z + BN_EPS)) + ee.z, 0.f);
    res.w = fmaxf((o.w - mm.w) * (gg.w / sqrtf(vv.w + BN_EPS)) + ee.w, 0.f);

    ((float4*)y)[(size_t)node * TPN + lc] = res;
}

// ---------------- aggregate BEFORE matmul: z = agg + self_norm * y_in ----------------
template <int D>
__global__ __launch_bounds__(256) void aggpre_k(const float* __restrict__ h,
                                                const int* __restrict__ rptr,
                                                const int2* __restrict__ pairs,
                                                const float* __restrict__ dinv,
                                                float* __restrict__ z, int n) {
    constexpr int TPN = D / 4;
    int npb = 256 / TPN;
    int node = blockIdx.x * npb + (int)(threadIdx.x / TPN);
    int lc = (int)(threadIdx.x % TPN);
    if (node >= n) return;

    int s = rptr[node], e = rptr[node + 1];
    float4 acc = make_float4(0.f, 0.f, 0.f, 0.f);
    for (int i = s; i < e; ++i) {
        int2 pr = pairs[i];
        float wv = __int_as_float(pr.y);
        float4 hv = ((const float4*)h)[(size_t)pr.x * TPN + lc];
        acc = fma4(wv, hv, acc);
    }
    float dv = dinv[node];
    float sn = dv * dv;
    float4 hs = ((const float4*)h)[(size_t)node * TPN + lc];
    acc.x = fmaf(sn, hs.x, acc.x);
    acc.y = fmaf(sn, hs.y, acc.y);
    acc.z = fmaf(sn, hs.z, acc.z);
    acc.w = fmaf(sn, hs.w, acc.w);
    ((float4*)z)[(size_t)node * TPN + lc] = acc;
}

// ---------------- parallel global mean pool (batch sorted) ----------------
__global__ __launch_bounds__(256) void pool2_k(const float* __restrict__ y,
                                               const int* __restrict__ batch,
                                               float* __restrict__ sums, int n) {
    const int NPB = 256;
    int node0 = blockIdx.x * NPB;
    int lc = threadIdx.x & 31;
    int nr = threadIdx.x >> 5;
    int end = node0 + NPB < n ? node0 + NPB : n;

    float4 acc = make_float4(0.f, 0.f, 0.f, 0.f);
    int curg = -1;
    for (int i = node0 + nr; i < end; i += 8) {
        int gph = batch[i];
        if (gph != curg) {
            if (curg >= 0) {
                float* dst = &sums[curg * 128 + lc * 4];
                atomicAdd(dst + 0, acc.x);
                atomicAdd(dst + 1, acc.y);
                atomicAdd(dst + 2, acc.z);
                atomicAdd(dst + 3, acc.w);
            }
            acc = make_float4(0.f, 0.f, 0.f, 0.f);
            curg = gph;
        }
        float4 hv = ((const float4*)y)[(size_t)i * 32 + lc];
        acc.x += hv.x; acc.y += hv.y; acc.z += hv.z; acc.w += hv.w;
    }
    if (curg >= 0) {
        float* dst = &sums[curg * 128 + lc * 4];
        atomicAdd(dst + 0, acc.x);
        atomicAdd(dst + 1, acc.y);
        atomicAdd(dst + 2, acc.z);
        atomicAdd(dst + 3, acc.w);
    }
}

__global__ void gcnt_k(const int* __restrict__ batch, float* __restrict__ rcnt, int n) {
    int gph = threadIdx.x;
    if (gph >= 64) return;
    int lo = 0, hi = n;
    while (lo < hi) { int mid = (lo + hi) >> 1; if (batch[mid] < gph) lo = mid + 1; else hi = mid; }
    int s = lo;
    lo = 0; hi = n;
    while (lo < hi) { int mid = (lo + hi) >> 1; if (batch[mid] < gph + 1) lo = mid + 1; else hi = mid; }
    int c = lo - s;
    rcnt[gph] = 1.0f / (c > 0 ? (float)c : 1.0f);
}

// ---------------- final FCs (tiny) ----------------
__global__ __launch_bounds__(256) void fc_k(const float* __restrict__ sums,
                                            const float* __restrict__ rcnt,
                                            const float* __restrict__ fcw,
                                            const float* __restrict__ fcb,
                                            const float* __restrict__ ow,
                                            const float* __restrict__ ob,
                                            float* __restrict__ out) {
    __shared__ float ps[64 * 128];
    __shared__ float hs[64 * 64];
    int t = threadIdx.x;
    for (int i = t; i < 64 * 128; i += 256) ps[i] = sums[i] * rcnt[i >> 7];
    __syncthreads();
    for (int idx = t; idx < 64 * 64; idx += 256) {
        int gph = idx >> 6, j = idx & 63;
        float a = fcb[j];
        for (int k = 0; k < 128; ++k) a = fmaf(ps[gph * 128 + k], fcw[k * 64 + j], a);
        hs[idx] = fmaxf(a, 0.f);
    }
    __syncthreads();
    if (t < 64) {
        float a = ob[0];
        for (int j = 0; j < 64; ++j) a = fmaf(hs[t * 64 + j], ow[j], a);
        out[t] = a;
    }
}

extern "C" void kernel_launch(void* const* d_in, const int* in_sizes, int n_in,
                              void* d_out, int out_size, void* d_ws, size_t ws_size,
                              hipStream_t stream) {
    const float* x     = (const float*)d_in[0];
    const int*   ei    = (const int*)d_in[1];
    const float* ew    = (const float*)d_in[2];
    const int*   batch = (const int*)d_in[3];
    const float* w1 = (const float*)d_in[4],  *b1 = (const float*)d_in[5];
    const float* g1 = (const float*)d_in[6],  *be1 = (const float*)d_in[7];
    const float* m1 = (const float*)d_in[8],  *v1 = (const float*)d_in[9];
    const float* w2 = (const float*)d_in[10], *b2 = (const float*)d_in[11];
    const float* g2 = (const float*)d_in[12], *be2 = (const float*)d_in[13];
    const float* m2 = (const float*)d_in[14], *v2 = (const float*)d_in[15];
    const float* w3 = (const float*)d_in[16], *b3 = (const float*)d_in[17];
    const float* g3 = (const float*)d_in[18], *be3 = (const float*)d_in[19];
    const float* m3 = (const float*)d_in[20], *v3 = (const float*)d_in[21];
    const float* fcw = (const float*)d_in[22], *fcb = (const float*)d_in[23];
    const float* ow  = (const float*)d_in[24], *ob  = (const float*)d_in[25];
    float* out = (float*)d_out;

    const int N = in_sizes[3];
    const int E = in_sizes[2];
    const int NB = (N + BKT - 1) >> NBSH;   // coarse buckets (<=1024 assumed)

    // workspace layout
    float* A    = (float*)d_ws;             // N x 128  (pairs0 aliased here pre-matmul)
    float* Bf   = A + (size_t)N * 128;      // N x 128
    float* dinv = Bf + (size_t)N * 128;     // N
    int*   rptr  = (int*)(dinv + N);        // N+1
    int*   chist = rptr + (N + 1);          // NB
    int*   cbase = chist + NB;              // NB+1
    int*   ccur  = cbase + NB + 1;          // NB
    int2*  pairs = (int2*)(ccur + NB);      // E (final CSR: {row, norm})
    float* sums  = (float*)(pairs + E);     // 64*128
    float* rcnt  = sums + 64 * 128;         // 64
    int2*  pairs0 = (int2*)A;               // E temp (dead before matmuls)

    hipMemsetAsync(chist, 0, NB * sizeof(int), stream);
    hipMemsetAsync(sums, 0, 64 * 128 * sizeof(float), stream);

    chist_k<<<256, 256, 0, stream>>>(ei, chist, E, NB);
    cscan_k<<<1, 1024, 0, stream>>>(chist, cbase, ccur, NB, rptr + N, E);
    cscat_k<<<256, 256, 0, stream>>>(ei, ew, ccur, pairs0, E, NB);
    fineA_k<<<NB, BKT, 0, stream>>>(pairs0, cbase, rptr, dinv, N);
    fineB_k<<<NB, BKT, 0, stream>>>(pairs0, cbase, rptr, dinv, pairs, N);

    // layer 1: matmul 64->32, then aggregate in 32-dim with BN/ReLU epilogue
    matmul_k<64, 32><<<(N + 63) / 64, 256, 0, stream>>>(x, w1, A, N);
    agg_k<32><<<(N + 31) / 32, 256, 0, stream>>>(A, rptr, pairs, dinv,
                                                 b1, g1, be1, m1, v1, Bf, N);
    // layer 2: aggregate in 32-dim, then matmul 32->64 with fused bias/BN/ReLU
    aggpre_k<32><<<(N + 31) / 32, 256, 0, stream>>>(Bf, rptr, pairs, dinv, A, N);
    matmulBN_k<32, 64><<<(N + 63) / 64, 256, 0, stream>>>(A, w2, b2, g2, be2, m2, v2, Bf, N);
    // layer 3: aggregate in 64-dim, then matmul 64->128 with fused bias/BN/ReLU
    aggpre_k<64><<<(N + 15) / 16, 256, 0, stream>>>(Bf, rptr, pairs, dinv, A, N);
    matmulBN_k<64, 128><<<(N + 63) / 64, 256, 0, stream>>>(A, w3, b3, g3, be3, m3, v3, Bf, N);

    pool2_k<<<(N + 255) / 256, 256, 0, stream>>>(Bf, batch, sums, N);
    gcnt_k<<<1, 64, 0, stream>>>(batch, rcnt, N);
    fc_k<<<1, 256, 0, stream>>>(sums, rcnt, fcw, fcb, ow, ob, out);
}

// Round 6
// 366.047 us; speedup vs baseline: 2.7510x; 1.0714x over previous
//
#include <hip/hip_runtime.h>
#include <math.h>

#define BN_EPS 1e-5f
#define NBSH 7          // 128 nodes per coarse bucket
#define BKT 128

__device__ __forceinline__ float4 fma4(float s, float4 a, float4 b) {
    return make_float4(fmaf(s, a.x, b.x), fmaf(s, a.y, b.y),
                       fmaf(s, a.z, b.z), fmaf(s, a.w, b.w));
}
__device__ __forceinline__ float4 add4(float4 a, float4 b) {
    return make_float4(a.x + b.x, a.y + b.y, a.z + b.z, a.w + b.w);
}

// ---------------- two-level counting sort: CSR by col ----------------

__global__ __launch_bounds__(256) void chist_k(const int* __restrict__ ei,
                                               int* __restrict__ chist, int E, int NB) {
    __shared__ int h[1024];
    int t = threadIdx.x;
    for (int i = t; i < NB; i += 256) h[i] = 0;
    __syncthreads();
    for (int e = blockIdx.x * 256 + t; e < E; e += gridDim.x * 256)
        atomicAdd(&h[((unsigned)ei[E + e]) >> NBSH], 1);
    __syncthreads();
    for (int i = t; i < NB; i += 256) if (h[i]) atomicAdd(&chist[i], h[i]);
}

__global__ __launch_bounds__(1024) void cscan_k(const int* __restrict__ chist,
                                                int* __restrict__ cbase,
                                                int* __restrict__ ccur,
                                                int NB, int* __restrict__ rptrN, int E) {
    __shared__ int s[1024];
    int t = threadIdx.x;
    int v = (t < NB) ? chist[t] : 0;
    s[t] = v;
    __syncthreads();
    for (int off = 1; off < 1024; off <<= 1) {
        int x = (t >= off) ? s[t - off] : 0;
        __syncthreads();
        s[t] += x;
        __syncthreads();
    }
    int excl = s[t] - v;
    if (t < NB) { cbase[t] = excl; ccur[t] = excl; }
    if (t == 0) { cbase[NB] = E; rptrN[0] = E; }
}

__global__ __launch_bounds__(256) void cscat_k(const int* __restrict__ ei,
                                               const float* __restrict__ ew,
                                               int* __restrict__ ccur,
                                               int2* __restrict__ pairs0, int E, int NB) {
    __shared__ int h[1024];
    __shared__ int base[1024];
    int t = threadIdx.x;
    int CH = (E + gridDim.x - 1) / gridDim.x;
    int lo = blockIdx.x * CH;
    int hi = lo + CH < E ? lo + CH : E;

    for (int i = t; i < NB; i += 256) h[i] = 0;
    __syncthreads();
    for (int e = lo + t; e < hi; e += 256)
        atomicAdd(&h[((unsigned)ei[E + e]) >> NBSH], 1);
    __syncthreads();
    for (int i = t; i < NB; i += 256) {
        int c = h[i];
        base[i] = c ? atomicAdd(&ccur[i], c) : 0;
        h[i] = 0;
    }
    __syncthreads();
    for (int e = lo + t; e < hi; e += 256) {
        int c = ei[E + e];
        int b = ((unsigned)c) >> NBSH;
        int idx = base[b] + atomicAdd(&h[b], 1);
        pairs0[idx] = make_int2(ei[e] | ((c & (BKT - 1)) << 17), __float_as_int(ew[e]));
    }
}

__global__ __launch_bounds__(BKT) void fineA_k(const int2* __restrict__ pairs0,
                                               const int* __restrict__ cbase,
                                               int* __restrict__ rptr,
                                               float* __restrict__ dinv, int N) {
    int b = blockIdx.x;
    __shared__ int cnt[BKT];
    __shared__ float wsum[BKT];
    __shared__ int sc[BKT];
    int t = threadIdx.x;
    cnt[t] = 0; wsum[t] = 0.f;
    __syncthreads();
    int s = cbase[b], e = cbase[b + 1];
    for (int i = s + t; i < e; i += BKT) {
        int2 p = pairs0[i];
        int cib = ((unsigned)p.x) >> 17;
        atomicAdd(&cnt[cib], 1);
        atomicAdd(&wsum[cib], __int_as_float(p.y));
    }
    __syncthreads();
    int v = cnt[t];
    sc[t] = v;
    __syncthreads();
    for (int off = 1; off < BKT; off <<= 1) {
        int x = (t >= off) ? sc[t - off] : 0;
        __syncthreads();
        sc[t] += x;
        __syncthreads();
    }
    int node = b * BKT + t;
    if (node < N) {
        rptr[node] = s + sc[t] - v;
        dinv[node] = 1.0f / sqrtf(wsum[t] + 1.0f);
    }
}

__global__ __launch_bounds__(BKT) void fineB_k(const int2* __restrict__ pairs0,
                                               const int* __restrict__ cbase,
                                               const int* __restrict__ rptr,
                                               const float* __restrict__ dinv,
                                               int2* __restrict__ pairs, int N) {
    int b = blockIdx.x;
    __shared__ int cur[BKT];
    __shared__ float dc[BKT];
    int t = threadIdx.x;
    int node = b * BKT + t;
    cur[t] = (node < N) ? rptr[node] : 0;
    dc[t] = (node < N) ? dinv[node] : 0.f;
    __syncthreads();
    int s = cbase[b], e = cbase[b + 1];
    for (int i = s + t; i < e; i += BKT) {
        int2 p = pairs0[i];
        int cib = ((unsigned)p.x) >> 17;
        int row = p.x & 0x1FFFF;
        float nw = dinv[row] * __int_as_float(p.y) * dc[cib];
        int pos = atomicAdd(&cur[cib], 1);
        pairs[pos] = make_int2(row, __float_as_int(nw));
    }
}

// ---------------- dense matmul h = x @ w (plain) ----------------
template <int DIN, int DOUT>
__global__ __launch_bounds__(256) void matmul_k(const float* __restrict__ x,
                                                const float* __restrict__ w,
                                                float* __restrict__ h, int n) {
    constexpr int RPB = 64;
    constexpr int XS = DIN + 4;
    constexpr int J = DOUT / 16;
    __shared__ float xs[RPB * XS];
    __shared__ float4 ws4[DIN * (DOUT / 4)];
    int t = threadIdx.x;
    int row0 = blockIdx.x * RPB;

    for (int i = t; i < DIN * DOUT / 4; i += 256) ws4[i] = ((const float4*)w)[i];
    for (int i = t; i < RPB * DIN / 4; i += 256) {
        int r = i / (DIN / 4), kq = i % (DIN / 4);
        int gr = row0 + r;
        float4 xv = (gr < n) ? ((const float4*)x)[(size_t)gr * (DIN / 4) + kq]
                             : make_float4(0.f, 0.f, 0.f, 0.f);
        *(float4*)&xs[r * XS + kq * 4] = xv;
    }
    __syncthreads();

    int r = t >> 2, cg = t & 3;
    float4 acc[J];
#pragma unroll
    for (int j = 0; j < J; ++j) acc[j] = make_float4(0.f, 0.f, 0.f, 0.f);

    for (int k = 0; k < DIN; ++k) {
        float xv = xs[r * XS + k];
#pragma unroll
        for (int j = 0; j < J; ++j) {
            float4 wv = ws4[k * (DOUT / 4) + cg + 4 * j];
            acc[j] = fma4(xv, wv, acc[j]);
        }
    }
    int gr = row0 + r;
    if (gr < n) {
#pragma unroll
        for (int j = 0; j < J; ++j)
            ((float4*)h)[(size_t)gr * (DOUT / 4) + cg + 4 * j] = acc[j];
    }
}

// ---------------- dense matmul with fused bias + BN + ReLU epilogue ----------------
template <int DIN, int DOUT>
__global__ __launch_bounds__(256) void matmulBN_k(const float* __restrict__ x,
                                                  const float* __restrict__ w,
                                                  const float* __restrict__ bias,
                                                  const float* __restrict__ g,
                                                  const float* __restrict__ be,
                                                  const float* __restrict__ m,
                                                  const float* __restrict__ v,
                                                  float* __restrict__ h, int n) {
    constexpr int RPB = 64;
    constexpr int XS = DIN + 4;
    constexpr int J = DOUT / 16;
    __shared__ float xs[RPB * XS];
    __shared__ float4 ws4[DIN * (DOUT / 4)];
    int t = threadIdx.x;
    int row0 = blockIdx.x * RPB;

    for (int i = t; i < DIN * DOUT / 4; i += 256) ws4[i] = ((const float4*)w)[i];
    for (int i = t; i < RPB * DIN / 4; i += 256) {
        int r = i / (DIN / 4), kq = i % (DIN / 4);
        int gr = row0 + r;
        float4 xv = (gr < n) ? ((const float4*)x)[(size_t)gr * (DIN / 4) + kq]
                             : make_float4(0.f, 0.f, 0.f, 0.f);
        *(float4*)&xs[r * XS + kq * 4] = xv;
    }
    __syncthreads();

    int r = t >> 2, cg = t & 3;
    float4 acc[J];
#pragma unroll
    for (int j = 0; j < J; ++j) acc[j] = make_float4(0.f, 0.f, 0.f, 0.f);

    for (int k = 0; k < DIN; ++k) {
        float xv = xs[r * XS + k];
#pragma unroll
        for (int j = 0; j < J; ++j) {
            float4 wv = ws4[k * (DOUT / 4) + cg + 4 * j];
            acc[j] = fma4(xv, wv, acc[j]);
        }
    }
    int gr = row0 + r;
    if (gr < n) {
#pragma unroll
        for (int j = 0; j < J; ++j) {
            int c4 = cg + 4 * j;
            float4 bb = ((const float4*)bias)[c4];
            float4 gg = ((const float4*)g)[c4];
            float4 ee = ((const float4*)be)[c4];
            float4 mm = ((const float4*)m)[c4];
            float4 vv = ((const float4*)v)[c4];
            float4 o = acc[j];
            float4 res;
            res.x = fmaxf((o.x + bb.x - mm.x) * (gg.x / sqrtf(vv.x + BN_EPS)) + ee.x, 0.f);
            res.y = fmaxf((o.y + bb.y - mm.y) * (gg.y / sqrtf(vv.y + BN_EPS)) + ee.y, 0.f);
            res.z = fmaxf((o.z + bb.z - mm.z) * (gg.z / sqrtf(vv.z + BN_EPS)) + ee.z, 0.f);
            res.w = fmaxf((o.w + bb.w - mm.w) * (gg.w / sqrtf(vv.w + BN_EPS)) + ee.w, 0.f);
            ((float4*)h)[(size_t)gr * (DOUT / 4) + c4] = res;
        }
    }
}

// -------- unrolled gather core: 4 independent accumulator chains --------
template <int TPN>
__device__ __forceinline__ float4 gather4(const float* __restrict__ h,
                                          const int2* __restrict__ pairs,
                                          int s, int e, int lc) {
    float4 a0 = make_float4(0.f, 0.f, 0.f, 0.f);
    float4 a1 = a0, a2 = a0, a3 = a0;
    int i = s;
    for (; i + 4 <= e; i += 4) {
        int2 p0 = pairs[i + 0];
        int2 p1 = pairs[i + 1];
        int2 p2 = pairs[i + 2];
        int2 p3 = pairs[i + 3];
        float4 h0 = ((const float4*)h)[(size_t)p0.x * TPN + lc];
        float4 h1 = ((const float4*)h)[(size_t)p1.x * TPN + lc];
        float4 h2 = ((const float4*)h)[(size_t)p2.x * TPN + lc];
        float4 h3 = ((const float4*)h)[(size_t)p3.x * TPN + lc];
        a0 = fma4(__int_as_float(p0.y), h0, a0);
        a1 = fma4(__int_as_float(p1.y), h1, a1);
        a2 = fma4(__int_as_float(p2.y), h2, a2);
        a3 = fma4(__int_as_float(p3.y), h3, a3);
    }
    for (; i < e; ++i) {
        int2 p = pairs[i];
        float4 hv = ((const float4*)h)[(size_t)p.x * TPN + lc];
        a0 = fma4(__int_as_float(p.y), hv, a0);
    }
    return add4(add4(a0, a1), add4(a2, a3));
}

// ---------------- aggregate AFTER matmul, fused bias+BN+ReLU (layer 1) ----------------
template <int D>
__global__ __launch_bounds__(256) void agg_k(const float* __restrict__ h,
                                             const int* __restrict__ rptr,
                                             const int2* __restrict__ pairs,
                                             const float* __restrict__ dinv,
                                             const float* __restrict__ bias,
                                             const float* __restrict__ g,
                                             const float* __restrict__ be,
                                             const float* __restrict__ m,
                                             const float* __restrict__ v,
                                             float* __restrict__ y, int n) {
    constexpr int TPN = D / 4;
    int npb = 256 / TPN;
    int node = blockIdx.x * npb + (int)(threadIdx.x / TPN);
    int lc = (int)(threadIdx.x % TPN);
    if (node >= n) return;

    int s = rptr[node], e = rptr[node + 1];
    float4 acc = gather4<TPN>(h, pairs, s, e, lc);

    float dv = dinv[node];
    float sn = dv * dv;
    float4 hs = ((const float4*)h)[(size_t)node * TPN + lc];
    float4 bb = ((const float4*)bias)[lc];
    float4 gg = ((const float4*)g)[lc];
    float4 ee = ((const float4*)be)[lc];
    float4 mm = ((const float4*)m)[lc];
    float4 vv = ((const float4*)v)[lc];

    float4 o;
    o.x = acc.x + sn * hs.x + bb.x;
    o.y = acc.y + sn * hs.y + bb.y;
    o.z = acc.z + sn * hs.z + bb.z;
    o.w = acc.w + sn * hs.w + bb.w;

    float4 res;
    res.x = fmaxf((o.x - mm.x) * (gg.x / sqrtf(vv.x + BN_EPS)) + ee.x, 0.f);
    res.y = fmaxf((o.y - mm.y) * (gg.y / sqrtf(vv.y + BN_EPS)) + ee.y, 0.f);
    res.z = fmaxf((o.z - mm.z) * (gg.z / sqrtf(vv.z + BN_EPS)) + ee.z, 0.f);
    res.w = fmaxf((o.w - mm.w) * (gg.w / sqrtf(vv.w + BN_EPS)) + ee.w, 0.f);

    ((float4*)y)[(size_t)node * TPN + lc] = res;
}

// ---------------- aggregate BEFORE matmul: z = agg + self_norm * y_in ----------------
template <int D>
__global__ __launch_bounds__(256) void aggpre_k(const float* __restrict__ h,
                                                const int* __restrict__ rptr,
                                                const int2* __restrict__ pairs,
                                                const float* __restrict__ dinv,
                                                float* __restrict__ z, int n) {
    constexpr int TPN = D / 4;
    int npb = 256 / TPN;
    int node = blockIdx.x * npb + (int)(threadIdx.x / TPN);
    int lc = (int)(threadIdx.x % TPN);
    if (node >= n) return;

    int s = rptr[node], e = rptr[node + 1];
    float4 acc = gather4<TPN>(h, pairs, s, e, lc);

    float dv = dinv[node];
    float sn = dv * dv;
    float4 hs = ((const float4*)h)[(size_t)node * TPN + lc];
    acc.x = fmaf(sn, hs.x, acc.x);
    acc.y = fmaf(sn, hs.y, acc.y);
    acc.z = fmaf(sn, hs.z, acc.z);
    acc.w = fmaf(sn, hs.w, acc.w);
    ((float4*)z)[(size_t)node * TPN + lc] = acc;
}

// ---------------- parallel global mean pool (batch sorted) ----------------
__global__ __launch_bounds__(256) void pool2_k(const float* __restrict__ y,
                                               const int* __restrict__ batch,
                                               float* __restrict__ sums, int n) {
    const int NPB = 256;
    int node0 = blockIdx.x * NPB;
    int lc = threadIdx.x & 31;
    int nr = threadIdx.x >> 5;
    int end = node0 + NPB < n ? node0 + NPB : n;

    float4 acc = make_float4(0.f, 0.f, 0.f, 0.f);
    int curg = -1;
    for (int i = node0 + nr; i < end; i += 8) {
        int gph = batch[i];
        if (gph != curg) {
            if (curg >= 0) {
                float* dst = &sums[curg * 128 + lc * 4];
                atomicAdd(dst + 0, acc.x);
                atomicAdd(dst + 1, acc.y);
                atomicAdd(dst + 2, acc.z);
                atomicAdd(dst + 3, acc.w);
            }
            acc = make_float4(0.f, 0.f, 0.f, 0.f);
            curg = gph;
        }
        float4 hv = ((const float4*)y)[(size_t)i * 32 + lc];
        acc.x += hv.x; acc.y += hv.y; acc.z += hv.z; acc.w += hv.w;
    }
    if (curg >= 0) {
        float* dst = &sums[curg * 128 + lc * 4];
        atomicAdd(dst + 0, acc.x);
        atomicAdd(dst + 1, acc.y);
        atomicAdd(dst + 2, acc.z);
        atomicAdd(dst + 3, acc.w);
    }
}

__global__ void gcnt_k(const int* __restrict__ batch, float* __restrict__ rcnt, int n) {
    int gph = threadIdx.x;
    if (gph >= 64) return;
    int lo = 0, hi = n;
    while (lo < hi) { int mid = (lo + hi) >> 1; if (batch[mid] < gph) lo = mid + 1; else hi = mid; }
    int s = lo;
    lo = 0; hi = n;
    while (lo < hi) { int mid = (lo + hi) >> 1; if (batch[mid] < gph + 1) lo = mid + 1; else hi = mid; }
    int c = lo - s;
    rcnt[gph] = 1.0f / (c > 0 ? (float)c : 1.0f);
}

// ---------------- final FCs (tiny) ----------------
__global__ __launch_bounds__(256) void fc_k(const float* __restrict__ sums,
                                            const float* __restrict__ rcnt,
                                            const float* __restrict__ fcw,
                                            const float* __restrict__ fcb,
                                            const float* __restrict__ ow,
                                            const float* __restrict__ ob,
                                            float* __restrict__ out) {
    __shared__ float ps[64 * 128];
    __shared__ float hs[64 * 64];
    int t = threadIdx.x;
    for (int i = t; i < 64 * 128; i += 256) ps[i] = sums[i] * rcnt[i >> 7];
    __syncthreads();
    for (int idx = t; idx < 64 * 64; idx += 256) {
        int gph = idx >> 6, j = idx & 63;
        float a = fcb[j];
        for (int k = 0; k < 128; ++k) a = fmaf(ps[gph * 128 + k], fcw[k * 64 + j], a);
        hs[idx] = fmaxf(a, 0.f);
    }
    __syncthreads();
    if (t < 64) {
        float a = ob[0];
        for (int j = 0; j < 64; ++j) a = fmaf(hs[t * 64 + j], ow[j], a);
        out[t] = a;
    }
}

extern "C" void kernel_launch(void* const* d_in, const int* in_sizes, int n_in,
                              void* d_out, int out_size, void* d_ws, size_t ws_size,
                              hipStream_t stream) {
    const float* x     = (const float*)d_in[0];
    const int*   ei    = (const int*)d_in[1];
    const float* ew    = (const float*)d_in[2];
    const int*   batch = (const int*)d_in[3];
    const float* w1 = (const float*)d_in[4],  *b1 = (const float*)d_in[5];
    const float* g1 = (const float*)d_in[6],  *be1 = (const float*)d_in[7];
    const float* m1 = (const float*)d_in[8],  *v1 = (const float*)d_in[9];
    const float* w2 = (const float*)d_in[10], *b2 = (const float*)d_in[11];
    const float* g2 = (const float*)d_in[12], *be2 = (const float*)d_in[13];
    const float* m2 = (const float*)d_in[14], *v2 = (const float*)d_in[15];
    const float* w3 = (const float*)d_in[16], *b3 = (const float*)d_in[17];
    const float* g3 = (const float*)d_in[18], *be3 = (const float*)d_in[19];
    const float* m3 = (const float*)d_in[20], *v3 = (const float*)d_in[21];
    const float* fcw = (const float*)d_in[22], *fcb = (const float*)d_in[23];
    const float* ow  = (const float*)d_in[24], *ob  = (const float*)d_in[25];
    float* out = (float*)d_out;

    const int N = in_sizes[3];
    const int E = in_sizes[2];
    const int NB = (N + BKT - 1) >> NBSH;

    // workspace layout
    float* A    = (float*)d_ws;             // N x 128  (pairs0 aliased here pre-matmul)
    float* Bf   = A + (size_t)N * 128;      // N x 128
    float* dinv = Bf + (size_t)N * 128;     // N
    int*   rptr  = (int*)(dinv + N);        // N+1
    int*   chist = rptr + (N + 1);          // NB
    int*   cbase = chist + NB;              // NB+1
    int*   ccur  = cbase + NB + 1;          // NB
    int2*  pairs = (int2*)(ccur + NB);      // E (final CSR: {row, norm})
    float* sums  = (float*)(pairs + E);     // 64*128
    float* rcnt  = sums + 64 * 128;         // 64
    int2*  pairs0 = (int2*)A;               // E temp (dead before matmuls)

    hipMemsetAsync(chist, 0, NB * sizeof(int), stream);
    hipMemsetAsync(sums, 0, 64 * 128 * sizeof(float), stream);

    chist_k<<<256, 256, 0, stream>>>(ei, chist, E, NB);
    cscan_k<<<1, 1024, 0, stream>>>(chist, cbase, ccur, NB, rptr + N, E);
    cscat_k<<<256, 256, 0, stream>>>(ei, ew, ccur, pairs0, E, NB);
    fineA_k<<<NB, BKT, 0, stream>>>(pairs0, cbase, rptr, dinv, N);
    fineB_k<<<NB, BKT, 0, stream>>>(pairs0, cbase, rptr, dinv, pairs, N);

    // layer 1: matmul 64->32, then aggregate in 32-dim with BN/ReLU epilogue
    matmul_k<64, 32><<<(N + 63) / 64, 256, 0, stream>>>(x, w1, A, N);
    agg_k<32><<<(N + 31) / 32, 256, 0, stream>>>(A, rptr, pairs, dinv,
                                                 b1, g1, be1, m1, v1, Bf, N);
    // layer 2: aggregate in 32-dim, then matmul 32->64 with fused bias/BN/ReLU
    aggpre_k<32><<<(N + 31) / 32, 256, 0, stream>>>(Bf, rptr, pairs, dinv, A, N);
    matmulBN_k<32, 64><<<(N + 63) / 64, 256, 0, stream>>>(A, w2, b2, g2, be2, m2, v2, Bf, N);
    // layer 3: aggregate in 64-dim, then matmul 64->128 with fused bias/BN/ReLU
    aggpre_k<64><<<(N + 15) / 16, 256, 0, stream>>>(Bf, rptr, pairs, dinv, A, N);
    matmulBN_k<64, 128><<<(N + 63) / 64, 256, 0, stream>>>(A, w3, b3, g3, be3, m3, v3, Bf, N);

    pool2_k<<<(N + 255) / 256, 256, 0, stream>>>(Bf, batch, sums, N);
    gcnt_k<<<1, 64, 0, stream>>>(batch, rcnt, N);
    fc_k<<<1, 256, 0, stream>>>(sums, rcnt, fcw, fcb, ow, ob, out);
}